// Round 5
// baseline (59359.772 us; speedup 1.0000x reference)
//
#include <hip/hip_runtime.h>
#include <math.h>

// B=256, T_ENC=200, D=256, T_MEL=1000, NMEL=80, R=5, IN_R=400, Td=200
#define ALIGN_OFF 20480000   // 256*200*400
#define FLSTRIDE 32          // u32s per flag line (128B padding)

__device__ __forceinline__ float sigf(float x) {
    return __builtin_amdgcn_rcpf(1.0f + __expf(-x));
}
__device__ __forceinline__ float tanhff(float x) {
    float e = __expf(2.0f * x);
    return 1.0f - 2.0f * __builtin_amdgcn_rcpf(e + 1.0f);
}

// ---------------------------------------------------------------------------
// 128x128-tile fp32 GEMM (prenet / processed_memory / mel) — unchanged.
// ---------------------------------------------------------------------------
template<int AMODE, int EPI>
__global__ __launch_bounds__(256)
void gemm128(const float* __restrict__ A, int lda,
             const float* __restrict__ W, int ldw,
             const float* __restrict__ bias,
             float* __restrict__ C, int ldc, int M, int N, int K)
{
    __shared__ float As[16][128];
    __shared__ float Bs[16][128];
    const int m0 = blockIdx.x * 128, n0 = blockIdx.y * 128;
    const int tid = threadIdx.x;
    const int tx = tid & 15, ty = tid >> 4;
    float acc[8][8] = {};
    for (int k0 = 0; k0 < K; k0 += 16) {
        {
            const int m = tid >> 1, h = (tid & 1) * 8;
            const int grow = m0 + m;
            float4 a0, a1;
            if (AMODE == 2) {
                int t = grow >> 8, b = grow & 255;
                if (t == 0) { a0 = make_float4(0, 0, 0, 0); a1 = a0; }
                else {
                    const float* p = A + (size_t)b * 80000 + (t - 1) * 400 + k0 + h;
                    a0 = *(const float4*)p; a1 = *(const float4*)(p + 4);
                }
            } else {
                const float* p = A + (size_t)grow * lda + k0 + h;
                a0 = *(const float4*)p; a1 = *(const float4*)(p + 4);
            }
            As[h + 0][m] = a0.x; As[h + 1][m] = a0.y; As[h + 2][m] = a0.z; As[h + 3][m] = a0.w;
            As[h + 4][m] = a1.x; As[h + 5][m] = a1.y; As[h + 6][m] = a1.z; As[h + 7][m] = a1.w;
            const int gn = n0 + m;
            float4 b0, b1;
            if (gn < N) {
                const float* p = W + (size_t)gn * ldw + k0 + h;
                b0 = *(const float4*)p; b1 = *(const float4*)(p + 4);
            } else { b0 = make_float4(0, 0, 0, 0); b1 = b0; }
            Bs[h + 0][m] = b0.x; Bs[h + 1][m] = b0.y; Bs[h + 2][m] = b0.z; Bs[h + 3][m] = b0.w;
            Bs[h + 4][m] = b1.x; Bs[h + 5][m] = b1.y; Bs[h + 6][m] = b1.z; Bs[h + 7][m] = b1.w;
        }
        __syncthreads();
        #pragma unroll
        for (int kk = 0; kk < 16; ++kk) {
            float av[8], bv[8];
            *(float4*)&av[0] = *(const float4*)&As[kk][ty * 8];
            *(float4*)&av[4] = *(const float4*)&As[kk][ty * 8 + 4];
            *(float4*)&bv[0] = *(const float4*)&Bs[kk][tx * 8];
            *(float4*)&bv[4] = *(const float4*)&Bs[kk][tx * 8 + 4];
            #pragma unroll
            for (int i = 0; i < 8; ++i)
                #pragma unroll
                for (int j = 0; j < 8; ++j)
                    acc[i][j] += av[i] * bv[j];
        }
        __syncthreads();
    }
    #pragma unroll
    for (int i = 0; i < 8; ++i) {
        const int row = m0 + ty * 8 + i;
        const int t_ = row >> 8, b_ = row & 255;
        #pragma unroll
        for (int j4 = 0; j4 < 2; ++j4) {
            const int col = n0 + tx * 8 + j4 * 4;
            if (col >= N) continue;
            float4 v;
            float* pv = &v.x;
            #pragma unroll
            for (int u = 0; u < 4; ++u) {
                float x = acc[i][j4 * 4 + u] + (bias ? bias[col + u] : 0.0f);
                if (EPI == 1) x = fmaxf(x, 0.0f);
                pv[u] = x;
            }
            if (EPI == 2) *(float4*)(C + (size_t)b_ * 80000 + t_ * 400 + col) = v;
            else          *(float4*)(C + (size_t)row * ldc + col) = v;
        }
    }
}

// ---------------------------------------------------------------------------
// Pack W [N][K] row-major -> P [K/4][N] float4 (k4-packed). One-time, tiny.
// ---------------------------------------------------------------------------
__global__ __launch_bounds__(256)
void pack_w(const float* __restrict__ W, float4* __restrict__ P, int N, int K)
{
    const int tot = N * (K >> 2);
    for (int i = blockIdx.x * 256 + threadIdx.x; i < tot; i += gridDim.x * 256) {
        const int n = i % N, k4 = i / N;
        P[(size_t)k4 * N + n] = *(const float4*)(W + (size_t)n * K + (k4 << 2));
    }
}

// ---------------------------------------------------------------------------
// Zero-RMW grid barrier (generation/flag based).
// Each block release-stores its own padded flag; block 0 polls all flags in
// parallel (threads 1..255), then release-stores `gen`; others acquire-spin
// on gen (read-only — no contended RMW anywhere).
// ---------------------------------------------------------------------------
__device__ __forceinline__ void gsync2(unsigned* flags, unsigned* gen,
                                       unsigned target, int bid, int tid)
{
    __syncthreads();
    if (bid == 0) {
        if (tid > 0 && tid < 256) {
            unsigned* f = flags + tid * FLSTRIDE;
            while ((int)(__hip_atomic_load(f, __ATOMIC_ACQUIRE, __HIP_MEMORY_SCOPE_AGENT) - target) < 0)
                __builtin_amdgcn_s_sleep(2);
        }
        __syncthreads();
        if (tid == 0) {
            __threadfence();
            __hip_atomic_store(gen, target, __ATOMIC_RELEASE, __HIP_MEMORY_SCOPE_AGENT);
        }
    } else {
        if (tid == 0) {
            __threadfence();
            __hip_atomic_store(flags + bid * FLSTRIDE, target, __ATOMIC_RELEASE, __HIP_MEMORY_SCOPE_AGENT);
            while ((int)(__hip_atomic_load(gen, __ATOMIC_ACQUIRE, __HIP_MEMORY_SCOPE_AGENT) - target) < 0)
                __builtin_amdgcn_s_sleep(2);
        }
    }
    __syncthreads();
}

// ---------------------------------------------------------------------------
// GRU phase, 768 threads, block tile = 4 rows x 64 cols, one gate per thread.
// k4-packed weights; coalesced 1KB/wave weight reads; LDS activations.
// ---------------------------------------------------------------------------
template<int KX, bool CONCAT>
__device__ __forceinline__ void gru2(
    float* smem, int bid, int tid,
    const float* __restrict__ xA, const float* __restrict__ xB,
    const float* __restrict__ hbuf,
    const float4* __restrict__ WihP, const float* __restrict__ bih,
    const float4* __restrict__ WhhP, const float* __restrict__ bhh,
    float* __restrict__ hout, float* __restrict__ res1)
{
    __syncthreads();
    const int br = bid >> 2, bc = bid & 3;
    const int r0 = br * 4, c0 = bc * 64;
    constexpr int XW = KX / 4;            // 96 (KX=384) or 64 (KX=256)
    float4* xs = (float4*)smem;           // [4][XW]
    float4* hs = xs + 4 * XW;             // [4][64]
    float*  pi_ = (float*)(hs + 256);     // [3][256]
    float*  ph_ = pi_ + 768;              // [3][256]
    for (int i = tid; i < 4 * XW; i += 768) {
        const int r = i / XW, k = i % XW;
        float4 v;
        if (CONCAT) {
            v = (k < 32) ? *(const float4*)(xA + (size_t)(r0 + r) * 128 + k * 4)
                         : *(const float4*)(xB + (size_t)(r0 + r) * 256 + (k - 32) * 4);
        } else {
            v = *(const float4*)(xA + (size_t)(r0 + r) * 256 + k * 4);
        }
        xs[i] = v;
    }
    if (tid < 256) {
        hs[tid] = *(const float4*)(hbuf + (size_t)(r0 + (tid >> 6)) * 256 + (tid & 63) * 4);
    }
    __syncthreads();
    {
        const int g = tid >> 8, idx = tid & 255;
        const int r4 = idx >> 6, cl = idx & 63;
        const int n = (g << 8) + c0 + cl;
        float ai = 0.f, ah = 0.f;
        const float4* xr = xs + r4 * XW;
        const float4* wp = WihP + n;
        #pragma unroll 8
        for (int k = 0; k < XW; ++k) {
            const float4 a = xr[k];
            const float4 w = wp[(size_t)k * 768];
            ai += a.x * w.x + a.y * w.y + a.z * w.z + a.w * w.w;
        }
        const float4* hr = hs + r4 * 64;
        const float4* wq = WhhP + n;
        #pragma unroll 8
        for (int k = 0; k < 64; ++k) {
            const float4 a = hr[k];
            const float4 w = wq[(size_t)k * 768];
            ah += a.x * w.x + a.y * w.y + a.z * w.z + a.w * w.w;
        }
        pi_[(g << 8) + idx] = ai + bih[n];
        ph_[(g << 8) + idx] = ah + bhh[n];
    }
    __syncthreads();
    if (tid < 256) {
        const int r4 = tid >> 6, cl = tid & 63;
        const int col = c0 + cl, row = r0 + r4;
        const float vr = sigf(pi_[tid] + ph_[tid]);
        const float vz = sigf(pi_[256 + tid] + ph_[256 + tid]);
        const float vn = tanhff(pi_[512 + tid] + vr * ph_[512 + tid]);
        const float hold = ((const float*)hs)[r4 * 256 + col];
        const float hp = (1.f - vz) * vn + vz * hold;
        hout[(size_t)row * 256 + col] = hp;
        if (res1) res1[(size_t)row * 256 + col] = hp + ((const float*)xs)[r4 * KX + col];
    }
}

// ---------------------------------------------------------------------------
// Persistent decoder loop: 256 blocks x 768 threads, 4 grid barriers / step.
// ---------------------------------------------------------------------------
__global__ __launch_bounds__(768)
void decoder_loop(
    const float* __restrict__ X2,    // [200][256][128]
    const float* __restrict__ pm,    // [256][200][256]
    const float* __restrict__ enc,   // [256][200][256]
    const int*   __restrict__ mlen,
    const float4* __restrict__ aWihP, const float* __restrict__ abih,
    const float4* __restrict__ aWhhP, const float* __restrict__ abhh,
    const float4* __restrict__ qWP,   const float* __restrict__ vW,
    const float4* __restrict__ pjWP,  const float* __restrict__ pjb,
    const float4* __restrict__ w1ihP, const float* __restrict__ w1bih,
    const float4* __restrict__ w1hhP, const float* __restrict__ w1bhh,
    const float4* __restrict__ w2ihP, const float* __restrict__ w2bih,
    const float4* __restrict__ w2hhP, const float* __restrict__ w2bhh,
    float* __restrict__ ha,   float* __restrict__ h1g, float* __restrict__ h2g,
    float* __restrict__ attb, float* __restrict__ d0g, float* __restrict__ d1g,
    float* __restrict__ dall, float* __restrict__ alout,
    unsigned* __restrict__ flags, unsigned* __restrict__ gen)
{
    __shared__ float smem[4608];
    const int bid = blockIdx.x, tid = threadIdx.x;
    const int br = bid >> 2, bc = bid & 3;
    const int r0 = br * 4, c0 = bc * 64;
    unsigned bt = 0;   // per-thread barrier count (uniform across all threads)

    for (int t = 0; t < 200; ++t) {
        const int pi = t & 1, po = pi ^ 1;
        const float* attP = attb + pi * 65536;
        float* attN = attb + po * 65536;
        const float* hnew = ha + po * 65536;

        // ---- P1: attention GRU: h_a' = GRU([x2_t | att], h_a) ----
        gru2<384, true>(smem, bid, tid,
            X2 + (size_t)t * 32768, attP, ha + pi * 65536,
            aWihP, abih, aWhhP, abhh, ha + po * 65536, nullptr);
        gsync2(flags, gen, ++bt, bid, tid);

        // ---- P2: Bahdanau attention (block = batch) ----
        {
            float* hv = smem;          // 256
            float* qv = hv + 256;      // 256
            float* vv = qv + 256;      // 256
            float* sc = vv + 256;      // 204
            float* al = sc + 204;      // 204
            float* part = al + 204;    // 768
            const int b = bid;
            if (tid < 256) hv[tid] = hnew[(size_t)b * 256 + tid];
            else if (tid < 512) vv[tid - 256] = vW[tid - 256];
            __syncthreads();
            if (tid < 256) {
                const float4* h4 = (const float4*)hv;
                const float4* qp = qWP + tid;
                float s = 0.f;
                #pragma unroll 8
                for (int k = 0; k < 64; ++k) {
                    const float4 a = h4[k];
                    const float4 w = qp[(size_t)k * 256];
                    s += a.x * w.x + a.y * w.y + a.z * w.z + a.w * w.w;
                }
                qv[tid] = s;
            }
            __syncthreads();
            const int wv = tid >> 6, ln = tid & 63;
            const int len = mlen[b];
            for (int i = wv; i < 200; i += 12) {
                const float4 pr = *(const float4*)(pm + ((size_t)b * 200 + i) * 256 + ln * 4);
                const float4 q4 = ((const float4*)qv)[ln];
                const float4 v4 = ((const float4*)vv)[ln];
                float p = v4.x * tanhff(pr.x + q4.x)
                        + v4.y * tanhff(pr.y + q4.y)
                        + v4.z * tanhff(pr.z + q4.z)
                        + v4.w * tanhff(pr.w + q4.w);
                #pragma unroll
                for (int off = 32; off; off >>= 1) p += __shfl_down(p, off);
                if (ln == 0) sc[i] = (i < len) ? p : -1e9f;
            }
            __syncthreads();
            if (wv == 0) {
                float v0 = sc[ln], v1 = sc[ln + 64], v2 = sc[ln + 128];
                float v3 = (ln < 8) ? sc[ln + 192] : -1e30f;
                float mx = fmaxf(fmaxf(v0, v1), fmaxf(v2, v3));
                #pragma unroll
                for (int off = 32; off; off >>= 1) mx = fmaxf(mx, __shfl_xor(mx, off));
                float e0 = __expf(v0 - mx), e1 = __expf(v1 - mx), e2 = __expf(v2 - mx);
                float e3 = (ln < 8) ? __expf(v3 - mx) : 0.f;
                float ss = e0 + e1 + e2 + e3;
                #pragma unroll
                for (int off = 32; off; off >>= 1) ss += __shfl_xor(ss, off);
                float inv = 1.0f / ss;
                float* ao = alout + (size_t)b * 40000 + (size_t)t * 200;
                al[ln]       = e0 * inv; ao[ln]       = e0 * inv;
                al[ln + 64]  = e1 * inv; ao[ln + 64]  = e1 * inv;
                al[ln + 128] = e2 * inv; ao[ln + 128] = e2 * inv;
                if (ln < 8) { al[ln + 192] = e3 * inv; ao[ln + 192] = e3 * inv; }
            }
            __syncthreads();
            {
                const int seg = tid >> 8, d = tid & 255;
                const int t0 = seg * 67, t1 = (seg == 2) ? 200 : t0 + 67;
                float a = 0.f;
                const float* er = enc + (size_t)b * 51200 + d;
                for (int tt = t0; tt < t1; ++tt) a += al[tt] * er[(size_t)tt * 256];
                part[seg * 256 + d] = a;
            }
            __syncthreads();
            if (tid < 256) {
                attN[(size_t)b * 256 + tid] = part[tid] + part[256 + tid] + part[512 + tid];
            }
        }
        gsync2(flags, gen, ++bt, bid, tid);

        // ---- P3: d0 = [h_a' | att'] @ pjW^T + pjb (split-K by 2) ----
        {
            float4* xs = (float4*)smem;            // [4][128]
            float* part = (float*)(xs + 512);      // [2][256]
            for (int i = tid; i < 512; i += 768) {
                const int r = i >> 7, k = i & 127;
                const float4 v = (k < 64)
                    ? *(const float4*)(hnew + (size_t)(r0 + r) * 256 + k * 4)
                    : *(const float4*)(attN + (size_t)(r0 + r) * 256 + (k - 64) * 4);
                xs[i] = v;
            }
            __syncthreads();
            if (tid < 512) {
                const int half = tid >> 8, idx = tid & 255;
                const int r4 = idx >> 6, cl = idx & 63;
                const float4* xr = xs + r4 * 128 + half * 64;
                const float4* wp = pjWP + (size_t)half * 64 * 256 + c0 + cl;
                float s = 0.f;
                #pragma unroll 8
                for (int k = 0; k < 64; ++k) {
                    const float4 a = xr[k];
                    const float4 w = wp[(size_t)k * 256];
                    s += a.x * w.x + a.y * w.y + a.z * w.z + a.w * w.w;
                }
                part[(half << 8) + idx] = s;
            }
            __syncthreads();
            if (tid < 256) {
                const int r4 = tid >> 6, cl = tid & 63;
                d0g[(size_t)(r0 + r4) * 256 + c0 + cl] =
                    part[tid] + part[256 + tid] + pjb[c0 + cl];
            }
        }
        gsync2(flags, gen, ++bt, bid, tid);

        // ---- P4: dec1 GRU + residual: d1 = h1' + d0 ----
        gru2<256, false>(smem, bid, tid,
            d0g, nullptr, h1g + pi * 65536,
            w1ihP, w1bih, w1hhP, w1bhh, h1g + po * 65536, d1g);
        gsync2(flags, gen, ++bt, bid, tid);

        // ---- P5: dec2 GRU + residual -> dall[t] ----
        gru2<256, false>(smem, bid, tid,
            d1g, nullptr, h2g + pi * 65536,
            w2ihP, w2bih, w2hhP, w2bhh, h2g + po * 65536,
            dall + (size_t)t * 65536);
        // no grid barrier: consumers are >=4 barriers away; smem hazard
        // handled by __syncthreads at gru2 entry
    }
}

// ---------------------------------------------------------------------------
extern "C" void kernel_launch(void* const* d_in, const int* in_sizes, int n_in,
                              void* d_out, int out_size, void* d_ws, size_t ws_size,
                              hipStream_t stream)
{
    const float* enc    = (const float*)d_in[0];
    const float* inputs = (const float*)d_in[1];
    const int*   mlen   = (const int*)d_in[2];
    const float* pW1 = (const float*)d_in[3];  const float* pb1 = (const float*)d_in[4];
    const float* pW2 = (const float*)d_in[5];  const float* pb2 = (const float*)d_in[6];
    const float* aWih = (const float*)d_in[7]; const float* abih = (const float*)d_in[8];
    const float* aWhh = (const float*)d_in[9]; const float* abhh = (const float*)d_in[10];
    const float* memW = (const float*)d_in[11];
    const float* qW   = (const float*)d_in[12];
    const float* vW   = (const float*)d_in[13];
    const float* pjW  = (const float*)d_in[14]; const float* pjb = (const float*)d_in[15];
    const float* w1ih = (const float*)d_in[16]; const float* w1bih = (const float*)d_in[17];
    const float* w1hh = (const float*)d_in[18]; const float* w1bhh = (const float*)d_in[19];
    const float* w2ih = (const float*)d_in[20]; const float* w2bih = (const float*)d_in[21];
    const float* w2hh = (const float*)d_in[22]; const float* w2bhh = (const float*)d_in[23];
    const float* melW = (const float*)d_in[24]; const float* melb = (const float*)d_in[25];

    float* out = (float*)d_out;
    float* ws  = (float*)d_ws;

    // workspace layout (floats)
    float* X2 = ws;                       // 200*256*128 = 6,553,600
    float* S  = X2 + 6553600;             // 10 x 65536 states
    float* ha   = S;
    float* h1g  = S + 2 * 65536;
    float* h2g  = S + 4 * 65536;
    float* attb = S + 6 * 65536;
    float* d0g  = S + 8 * 65536;
    float* d1g  = S + 9 * 65536;
    unsigned* flags = (unsigned*)(S + 655360);   // 256*32 u32 = 8192
    unsigned* gen   = flags + 8192;              // + pad to 16384 total
    float* X1 = S + 655360 + 16384;       // 13,107,200 (aliased as dall)
    float* pmw = X1 + 13107200;           // 13,107,200
    float* dall = X1;
    // packed weights after pmw
    float* pk = pmw + 13107200;
    float4* aWihP = (float4*)pk;              // 96*768  = 73728 f4
    float4* aWhhP = aWihP + 73728;            // 64*768  = 49152
    float4* w1ihP = aWhhP + 49152;            // 49152
    float4* w1hhP = w1ihP + 49152;            // 49152
    float4* w2ihP = w1hhP + 49152;            // 49152
    float4* w2hhP = w2ihP + 49152;            // 49152
    float4* pjWP  = w2hhP + 49152;            // 128*256 = 32768
    float4* qWP   = pjWP + 32768;             // 64*256  = 16384

    // zero initial states + sync area (flags/gen)
    hipMemsetAsync(S, 0, (655360 + 16384) * sizeof(float), stream);

    // pack weights into [K/4][N] float4 layout (one-time, tiny)
    pack_w<<<64, 256, 0, stream>>>(aWih, aWihP, 768, 384);
    pack_w<<<64, 256, 0, stream>>>(aWhh, aWhhP, 768, 256);
    pack_w<<<64, 256, 0, stream>>>(w1ih, w1ihP, 768, 256);
    pack_w<<<64, 256, 0, stream>>>(w1hh, w1hhP, 768, 256);
    pack_w<<<64, 256, 0, stream>>>(w2ih, w2ihP, 768, 256);
    pack_w<<<64, 256, 0, stream>>>(w2hh, w2hhP, 768, 256);
    pack_w<<<64, 256, 0, stream>>>(pjW,  pjWP,  256, 512);
    pack_w<<<64, 256, 0, stream>>>(qW,   qWP,   256, 256);

    // prenet1: X1 = relu(prev @ W1^T + b1)  [51200,256]
    gemm128<2, 1><<<dim3(400, 2), 256, 0, stream>>>(
        inputs, 0, pW1, 400, pb1, X1, 256, 51200, 256, 400);
    // prenet2: X2 = relu(X1 @ W2^T + b2)  [51200,128]
    gemm128<0, 1><<<dim3(400, 1), 256, 0, stream>>>(
        X1, 256, pW2, 256, pb2, X2, 128, 51200, 128, 256);
    // processed_memory = enc @ memW^T  [51200,256]
    gemm128<0, 0><<<dim3(400, 2), 256, 0, stream>>>(
        enc, 256, memW, 256, nullptr, pmw, 256, 51200, 256, 256);

    // the 200-step sequential decoder
    decoder_loop<<<256, 768, 0, stream>>>(
        X2, pmw, enc, mlen,
        aWihP, abih, aWhhP, abhh, qWP, vW, pjWP, pjb,
        w1ihP, w1bih, w1hhP, w1bhh, w2ihP, w2bih, w2hhP, w2bhh,
        ha, h1g, h2g, attb, d0g, d1g, dall, out + ALIGN_OFF, flags, gen);

    // mel projection: out[b,t,:] = dall[t,b,:] @ melW^T + melb
    gemm128<0, 2><<<dim3(400, 4), 256, 0, stream>>>(
        dall, 256, melW, 256, melb, out, 400, 51200, 400, 256);
}

// Round 6
// 48863.745 us; speedup vs baseline: 1.2148x; 1.2148x over previous
//
#include <hip/hip_runtime.h>
#include <math.h>

// B=256, T_ENC=200, D=256, T_MEL=1000, NMEL=80, R=5, IN_R=400, Td=200
#define ALIGN_OFF 20480000   // 256*200*400
#define FLSTRIDE 32          // u32s per flag line (128B padding)
#define BPG 32               // blocks per group (8 groups of 32)

__device__ __forceinline__ float sigf(float x) {
    return __builtin_amdgcn_rcpf(1.0f + __expf(-x));
}
__device__ __forceinline__ float tanhff(float x) {
    float e = __expf(2.0f * x);
    return 1.0f - 2.0f * __builtin_amdgcn_rcpf(e + 1.0f);
}
__device__ __forceinline__ unsigned short f2bf(float x) {
    unsigned u = __float_as_uint(x);
    return (unsigned short)((u + 0x7FFFu + ((u >> 16) & 1u)) >> 16);
}
__device__ __forceinline__ float bf2f(unsigned short h) {
    return __uint_as_float(((unsigned)h) << 16);
}

// ---------------------------------------------------------------------------
// 128x128-tile fp32 GEMM.
// AMODE: 0 plain; 2 teacher-forcing virtual A (prenet1)
// EPI: 0 plain, 1 relu, 2 mel-layout store, 3 bf16 store (ldc fixed 256)
// ---------------------------------------------------------------------------
template<int AMODE, int EPI>
__global__ __launch_bounds__(256)
void gemm128(const float* __restrict__ A, int lda,
             const float* __restrict__ W, int ldw,
             const float* __restrict__ bias,
             float* __restrict__ C, int ldc, int M, int N, int K)
{
    __shared__ float As[16][128];
    __shared__ float Bs[16][128];
    const int m0 = blockIdx.x * 128, n0 = blockIdx.y * 128;
    const int tid = threadIdx.x;
    const int tx = tid & 15, ty = tid >> 4;
    float acc[8][8] = {};
    for (int k0 = 0; k0 < K; k0 += 16) {
        {
            const int m = tid >> 1, h = (tid & 1) * 8;
            const int grow = m0 + m;
            float4 a0, a1;
            if (AMODE == 2) {
                int t = grow >> 8, b = grow & 255;
                if (t == 0) { a0 = make_float4(0, 0, 0, 0); a1 = a0; }
                else {
                    const float* p = A + (size_t)b * 80000 + (t - 1) * 400 + k0 + h;
                    a0 = *(const float4*)p; a1 = *(const float4*)(p + 4);
                }
            } else {
                const float* p = A + (size_t)grow * lda + k0 + h;
                a0 = *(const float4*)p; a1 = *(const float4*)(p + 4);
            }
            As[h + 0][m] = a0.x; As[h + 1][m] = a0.y; As[h + 2][m] = a0.z; As[h + 3][m] = a0.w;
            As[h + 4][m] = a1.x; As[h + 5][m] = a1.y; As[h + 6][m] = a1.z; As[h + 7][m] = a1.w;
            const int gn = n0 + m;
            float4 b0, b1;
            if (gn < N) {
                const float* p = W + (size_t)gn * ldw + k0 + h;
                b0 = *(const float4*)p; b1 = *(const float4*)(p + 4);
            } else { b0 = make_float4(0, 0, 0, 0); b1 = b0; }
            Bs[h + 0][m] = b0.x; Bs[h + 1][m] = b0.y; Bs[h + 2][m] = b0.z; Bs[h + 3][m] = b0.w;
            Bs[h + 4][m] = b1.x; Bs[h + 5][m] = b1.y; Bs[h + 6][m] = b1.z; Bs[h + 7][m] = b1.w;
        }
        __syncthreads();
        #pragma unroll
        for (int kk = 0; kk < 16; ++kk) {
            float av[8], bv[8];
            *(float4*)&av[0] = *(const float4*)&As[kk][ty * 8];
            *(float4*)&av[4] = *(const float4*)&As[kk][ty * 8 + 4];
            *(float4*)&bv[0] = *(const float4*)&Bs[kk][tx * 8];
            *(float4*)&bv[4] = *(const float4*)&Bs[kk][tx * 8 + 4];
            #pragma unroll
            for (int i = 0; i < 8; ++i)
                #pragma unroll
                for (int j = 0; j < 8; ++j)
                    acc[i][j] += av[i] * bv[j];
        }
        __syncthreads();
    }
    #pragma unroll
    for (int i = 0; i < 8; ++i) {
        const int row = m0 + ty * 8 + i;
        const int t_ = row >> 8, b_ = row & 255;
        #pragma unroll
        for (int j4 = 0; j4 < 2; ++j4) {
            const int col = n0 + tx * 8 + j4 * 4;
            if (col >= N) continue;
            float4 v;
            float* pv = &v.x;
            #pragma unroll
            for (int u = 0; u < 4; ++u) {
                float x = acc[i][j4 * 4 + u] + (bias ? bias[col + u] : 0.0f);
                if (EPI == 1) x = fmaxf(x, 0.0f);
                pv[u] = x;
            }
            if (EPI == 2)      *(float4*)(C + (size_t)b_ * 80000 + t_ * 400 + col) = v;
            else if (EPI == 3) {
                ushort4 o;
                o.x = f2bf(pv[0]); o.y = f2bf(pv[1]); o.z = f2bf(pv[2]); o.w = f2bf(pv[3]);
                *(ushort4*)((unsigned short*)C + (size_t)row * 256 + col) = o;
            } else             *(float4*)(C + (size_t)row * ldc + col) = v;
        }
    }
}

// ---------------------------------------------------------------------------
// Pack W [N][K] -> P [K/4][N] float4 (k4-packed).
// ---------------------------------------------------------------------------
__global__ __launch_bounds__(256)
void pack_w(const float* __restrict__ W, float4* __restrict__ P, int N, int K)
{
    const int tot = N * (K >> 2);
    for (int i = blockIdx.x * 256 + threadIdx.x; i < tot; i += gridDim.x * 256) {
        const int n = i % N, k4 = i / N;
        P[(size_t)k4 * N + n] = *(const float4*)(W + (size_t)n * K + (k4 << 2));
    }
}

// fp32 -> bf16 elementwise pack (n multiple of 4)
__global__ __launch_bounds__(256)
void pack_bf16(const float* __restrict__ src, unsigned short* __restrict__ dst, int n)
{
    for (int i = (blockIdx.x * 256 + threadIdx.x) * 4; i < n; i += gridDim.x * 1024) {
        float4 v = *(const float4*)(src + i);
        ushort4 o;
        o.x = f2bf(v.x); o.y = f2bf(v.y); o.z = f2bf(v.z); o.w = f2bf(v.w);
        *(ushort4*)(dst + i) = o;
    }
}

// ---------------------------------------------------------------------------
// Per-group barrier (32 blocks). Relaxed polling; exactly ONE release fence
// before signaling and ONE acquire fence after passing — no per-iteration
// cache invalidation (the round-4/5 stall: acquire-in-loop emits buffer_inv
// each poll, wiping L1/L2 continuously).
// ---------------------------------------------------------------------------
__device__ __forceinline__ void gsync3(unsigned* flags, unsigned* gen,
                                       unsigned target, int g, int j, int tid)
{
    __syncthreads();
    if (j == 0) {
        if (tid >= 1 && tid < BPG) {
            const unsigned* f = flags + (size_t)(g * BPG + tid) * FLSTRIDE;
            while ((int)(__hip_atomic_load(f, __ATOMIC_RELAXED, __HIP_MEMORY_SCOPE_AGENT) - target) < 0)
                __builtin_amdgcn_s_sleep(1);
        }
        __syncthreads();
        if (tid == 0) {
            __builtin_amdgcn_fence(__ATOMIC_ACQ_REL, "agent");
            __hip_atomic_store(gen + (size_t)g * FLSTRIDE, target, __ATOMIC_RELAXED, __HIP_MEMORY_SCOPE_AGENT);
        }
    } else {
        if (tid == 0) {
            __builtin_amdgcn_fence(__ATOMIC_RELEASE, "agent");
            __hip_atomic_store(flags + (size_t)(g * BPG + j) * FLSTRIDE, target, __ATOMIC_RELAXED, __HIP_MEMORY_SCOPE_AGENT);
            const unsigned* gp = gen + (size_t)g * FLSTRIDE;
            while ((int)(__hip_atomic_load(gp, __ATOMIC_RELAXED, __HIP_MEMORY_SCOPE_AGENT) - target) < 0)
                __builtin_amdgcn_s_sleep(1);
        }
    }
    __syncthreads();
    __builtin_amdgcn_fence(__ATOMIC_ACQUIRE, "agent");
}

// ---------------------------------------------------------------------------
// GRU phase: block handles 4 rows x 64 gate-cols, one gate per thread-third.
// ---------------------------------------------------------------------------
template<int KX, bool CONCAT>
__device__ __forceinline__ void gru2(
    float* smem, int r0, int c0, int tid,
    const float* __restrict__ xA, const float* __restrict__ xB,
    const float* __restrict__ hbuf,
    const float4* __restrict__ WihP, const float* __restrict__ bih,
    const float4* __restrict__ WhhP, const float* __restrict__ bhh,
    float* __restrict__ hout, float* __restrict__ res1)
{
    __syncthreads();
    constexpr int XW = KX / 4;            // 96 (KX=384) or 64 (KX=256)
    float4* xs = (float4*)smem;           // [4][XW]
    float4* hs = xs + 4 * XW;             // [4][64]
    float*  pi_ = (float*)(hs + 256);     // [3][256]
    float*  ph_ = pi_ + 768;              // [3][256]
    for (int i = tid; i < 4 * XW; i += 768) {
        const int r = i / XW, k = i % XW;
        float4 v;
        if (CONCAT) {
            v = (k < 32) ? *(const float4*)(xA + (size_t)(r0 + r) * 128 + k * 4)
                         : *(const float4*)(xB + (size_t)(r0 + r) * 256 + (k - 32) * 4);
        } else {
            v = *(const float4*)(xA + (size_t)(r0 + r) * 256 + k * 4);
        }
        xs[i] = v;
    }
    if (tid < 256) {
        hs[tid] = *(const float4*)(hbuf + (size_t)(r0 + (tid >> 6)) * 256 + (tid & 63) * 4);
    }
    __syncthreads();
    {
        const int g = tid >> 8, idx = tid & 255;
        const int r4 = idx >> 6, cl = idx & 63;
        const int n = (g << 8) + c0 + cl;
        float ai = 0.f, ah = 0.f;
        const float4* xr = xs + r4 * XW;
        const float4* wp = WihP + n;
        #pragma unroll 8
        for (int k = 0; k < XW; ++k) {
            const float4 a = xr[k];
            const float4 w = wp[(size_t)k * 768];
            ai += a.x * w.x + a.y * w.y + a.z * w.z + a.w * w.w;
        }
        const float4* hr = hs + r4 * 64;
        const float4* wq = WhhP + n;
        #pragma unroll 8
        for (int k = 0; k < 64; ++k) {
            const float4 a = hr[k];
            const float4 w = wq[(size_t)k * 768];
            ah += a.x * w.x + a.y * w.y + a.z * w.z + a.w * w.w;
        }
        pi_[(g << 8) + idx] = ai + bih[n];
        ph_[(g << 8) + idx] = ah + bhh[n];
    }
    __syncthreads();
    if (tid < 256) {
        const int r4 = tid >> 6, cl = tid & 63;
        const int col = c0 + cl, row = r0 + r4;
        const float vr = sigf(pi_[tid] + ph_[tid]);
        const float vz = sigf(pi_[256 + tid] + ph_[256 + tid]);
        const float vn = tanhff(pi_[512 + tid] + vr * ph_[512 + tid]);
        const float hold = ((const float*)hs)[r4 * 256 + col];
        const float hp = (1.f - vz) * vn + vz * hold;
        hout[(size_t)row * 256 + col] = hp;
        if (res1) res1[(size_t)row * 256 + col] = hp + ((const float*)xs)[r4 * KX + col];
    }
}

// ---------------------------------------------------------------------------
// Persistent decoder: 8 independent groups of 32 blocks (group = bid%8 ->
// likely one XCD). Batch rows are group-private, so no cross-group sync.
// ---------------------------------------------------------------------------
__global__ __launch_bounds__(768)
void decoder_loop(
    const float* __restrict__ X2,            // [200][256][128]
    const unsigned short* __restrict__ pmH,  // [256][200][256] bf16
    const unsigned short* __restrict__ encH, // [256][200][256] bf16
    const int*   __restrict__ mlen,
    const float4* __restrict__ aWihP, const float* __restrict__ abih,
    const float4* __restrict__ aWhhP, const float* __restrict__ abhh,
    const float4* __restrict__ qWP,   const float* __restrict__ vW,
    const float4* __restrict__ pjWP,  const float* __restrict__ pjb,
    const float4* __restrict__ w1ihP, const float* __restrict__ w1bih,
    const float4* __restrict__ w1hhP, const float* __restrict__ w1bhh,
    const float4* __restrict__ w2ihP, const float* __restrict__ w2bih,
    const float4* __restrict__ w2hhP, const float* __restrict__ w2bhh,
    float* __restrict__ ha,   float* __restrict__ h1g, float* __restrict__ h2g,
    float* __restrict__ attb, float* __restrict__ d0g, float* __restrict__ d1g,
    float* __restrict__ dall, float* __restrict__ alout,
    unsigned* __restrict__ flags, unsigned* __restrict__ gen)
{
    __shared__ float smem[4608];
    const int bid = blockIdx.x, tid = threadIdx.x;
    const int g = bid & 7, j = bid >> 3;        // group, member
    const int rowbase = g * 32;
    const int jr = j >> 2, jc = j & 3;
    const int r0 = rowbase + jr * 4, c0 = jc * 64;
    const int batt = rowbase + j;               // P2 batch row
    unsigned bt = 0;

    for (int t = 0; t < 200; ++t) {
        const int pi = t & 1, po = pi ^ 1;
        const float* attP = attb + pi * 65536;
        float* attN = attb + po * 65536;
        const float* hnew = ha + po * 65536;

        // ---- P1: attention GRU ----
        gru2<384, true>(smem, r0, c0, tid,
            X2 + (size_t)t * 32768, attP, ha + pi * 65536,
            aWihP, abih, aWhhP, abhh, ha + po * 65536, nullptr);
        gsync3(flags, gen, ++bt, g, j, tid);

        // ---- P2: Bahdanau attention (block = one batch row) ----
        {
            float* hv = smem;          // 256
            float* qv = hv + 256;      // 256
            float* vv = qv + 256;      // 256
            float* sc = vv + 256;      // 208
            float* al = sc + 208;      // 208
            float* part = al + 208;    // [12][256] (16B-aligned: off 1184)
            const int b = batt;
            if (tid < 256) hv[tid] = hnew[(size_t)b * 256 + tid];
            else if (tid < 512) vv[tid - 256] = vW[tid - 256];
            __syncthreads();
            if (tid < 256) {
                const float4* h4 = (const float4*)hv;
                const float4* qp = qWP + tid;
                float s = 0.f;
                #pragma unroll 8
                for (int k = 0; k < 64; ++k) {
                    const float4 a = h4[k];
                    const float4 w = qp[(size_t)k * 256];
                    s += a.x * w.x + a.y * w.y + a.z * w.z + a.w * w.w;
                }
                qv[tid] = s;
            }
            __syncthreads();
            const int wv = tid >> 6, ln = tid & 63;
            const int len = mlen[b];
            {
                const float4 q4 = ((const float4*)qv)[ln];
                const float4 v4 = ((const float4*)vv)[ln];
                #pragma unroll 2
                for (int i = wv; i < 200; i += 12) {
                    const ushort4 pr = *(const ushort4*)(pmH + ((size_t)b * 200 + i) * 256 + ln * 4);
                    float p = v4.x * tanhff(bf2f(pr.x) + q4.x)
                            + v4.y * tanhff(bf2f(pr.y) + q4.y)
                            + v4.z * tanhff(bf2f(pr.z) + q4.z)
                            + v4.w * tanhff(bf2f(pr.w) + q4.w);
                    #pragma unroll
                    for (int off = 32; off; off >>= 1) p += __shfl_down(p, off);
                    if (ln == 0) sc[i] = (i < len) ? p : -1e9f;
                }
            }
            __syncthreads();
            if (wv == 0) {
                float v0 = sc[ln], v1 = sc[ln + 64], v2 = sc[ln + 128];
                float v3 = (ln < 8) ? sc[ln + 192] : -1e30f;
                float mx = fmaxf(fmaxf(v0, v1), fmaxf(v2, v3));
                #pragma unroll
                for (int off = 32; off; off >>= 1) mx = fmaxf(mx, __shfl_xor(mx, off));
                float e0 = __expf(v0 - mx), e1 = __expf(v1 - mx), e2 = __expf(v2 - mx);
                float e3 = (ln < 8) ? __expf(v3 - mx) : 0.f;
                float ss = e0 + e1 + e2 + e3;
                #pragma unroll
                for (int off = 32; off; off >>= 1) ss += __shfl_xor(ss, off);
                float inv = 1.0f / ss;
                float* ao = alout + (size_t)b * 40000 + (size_t)t * 200;
                al[ln]       = e0 * inv; ao[ln]       = e0 * inv;
                al[ln + 64]  = e1 * inv; ao[ln + 64]  = e1 * inv;
                al[ln + 128] = e2 * inv; ao[ln + 128] = e2 * inv;
                if (ln < 8) { al[ln + 192] = e3 * inv; ao[ln + 192] = e3 * inv; }
            }
            __syncthreads();
            {
                float a0 = 0.f, a1 = 0.f, a2 = 0.f, a3 = 0.f;
                #pragma unroll 2
                for (int i = wv; i < 200; i += 12) {
                    const float w = al[i];
                    const ushort4 ev = *(const ushort4*)(encH + ((size_t)b * 200 + i) * 256 + ln * 4);
                    a0 = fmaf(w, bf2f(ev.x), a0);
                    a1 = fmaf(w, bf2f(ev.y), a1);
                    a2 = fmaf(w, bf2f(ev.z), a2);
                    a3 = fmaf(w, bf2f(ev.w), a3);
                }
                ((float4*)part)[wv * 64 + ln] = make_float4(a0, a1, a2, a3);
            }
            __syncthreads();
            if (tid < 256) {
                float s = 0.f;
                #pragma unroll
                for (int w2 = 0; w2 < 12; ++w2) s += part[w2 * 256 + tid];
                attN[(size_t)b * 256 + tid] = s;
            }
        }
        gsync3(flags, gen, ++bt, g, j, tid);

        // ---- P3: d0 = [h_a' | att'] @ pjW^T + pjb (split-K by 2) ----
        {
            float4* xs = (float4*)smem;            // [4][128]
            float* part = (float*)(xs + 512);      // [2][256]
            for (int i = tid; i < 512; i += 768) {
                const int r = i >> 7, k = i & 127;
                const float4 v = (k < 64)
                    ? *(const float4*)(hnew + (size_t)(r0 + r) * 256 + k * 4)
                    : *(const float4*)(attN + (size_t)(r0 + r) * 256 + (k - 64) * 4);
                xs[i] = v;
            }
            __syncthreads();
            if (tid < 512) {
                const int half = tid >> 8, idx = tid & 255;
                const int r4 = idx >> 6, cl = idx & 63;
                const float4* xr = xs + r4 * 128 + half * 64;
                const float4* wp = pjWP + (size_t)half * 64 * 256 + c0 + cl;
                float s = 0.f;
                #pragma unroll 8
                for (int k = 0; k < 64; ++k) {
                    const float4 a = xr[k];
                    const float4 w = wp[(size_t)k * 256];
                    s += a.x * w.x + a.y * w.y + a.z * w.z + a.w * w.w;
                }
                part[(half << 8) + idx] = s;
            }
            __syncthreads();
            if (tid < 256) {
                const int r4 = tid >> 6, cl = tid & 63;
                d0g[(size_t)(r0 + r4) * 256 + c0 + cl] =
                    part[tid] + part[256 + tid] + pjb[c0 + cl];
            }
        }
        gsync3(flags, gen, ++bt, g, j, tid);

        // ---- P4: dec1 GRU + residual ----
        gru2<256, false>(smem, r0, c0, tid,
            d0g, nullptr, h1g + pi * 65536,
            w1ihP, w1bih, w1hhP, w1bhh, h1g + po * 65536, d1g);
        gsync3(flags, gen, ++bt, g, j, tid);

        // ---- P5: dec2 GRU + residual -> dall[t] ----
        gru2<256, false>(smem, r0, c0, tid,
            d1g, nullptr, h2g + pi * 65536,
            w2ihP, w2bih, w2hhP, w2bhh, h2g + po * 65536,
            dall + (size_t)t * 65536);
        // no group barrier: consumers >=4 barriers away; smem hazard covered
        // by __syncthreads at gru2 entry
    }
}

// ---------------------------------------------------------------------------
extern "C" void kernel_launch(void* const* d_in, const int* in_sizes, int n_in,
                              void* d_out, int out_size, void* d_ws, size_t ws_size,
                              hipStream_t stream)
{
    const float* enc    = (const float*)d_in[0];
    const float* inputs = (const float*)d_in[1];
    const int*   mlen   = (const int*)d_in[2];
    const float* pW1 = (const float*)d_in[3];  const float* pb1 = (const float*)d_in[4];
    const float* pW2 = (const float*)d_in[5];  const float* pb2 = (const float*)d_in[6];
    const float* aWih = (const float*)d_in[7]; const float* abih = (const float*)d_in[8];
    const float* aWhh = (const float*)d_in[9]; const float* abhh = (const float*)d_in[10];
    const float* memW = (const float*)d_in[11];
    const float* qW   = (const float*)d_in[12];
    const float* vW   = (const float*)d_in[13];
    const float* pjW  = (const float*)d_in[14]; const float* pjb = (const float*)d_in[15];
    const float* w1ih = (const float*)d_in[16]; const float* w1bih = (const float*)d_in[17];
    const float* w1hh = (const float*)d_in[18]; const float* w1bhh = (const float*)d_in[19];
    const float* w2ih = (const float*)d_in[20]; const float* w2bih = (const float*)d_in[21];
    const float* w2hh = (const float*)d_in[22]; const float* w2bhh = (const float*)d_in[23];
    const float* melW = (const float*)d_in[24]; const float* melb = (const float*)d_in[25];

    float* out = (float*)d_out;
    float* ws  = (float*)d_ws;

    // workspace layout (floats) — total ~34.9M floats (same as round 5)
    float* X2 = ws;                       // 6,553,600
    float* S  = X2 + 6553600;             // 10 x 65536 states
    float* ha   = S;
    float* h1g  = S + 2 * 65536;
    float* h2g  = S + 4 * 65536;
    float* attb = S + 6 * 65536;
    float* d0g  = S + 8 * 65536;
    float* d1g  = S + 9 * 65536;
    unsigned* flags = (unsigned*)(S + 655360);   // 8192 u32
    unsigned* gen   = flags + 8192;              // 1024 u32 (within 16384 pad)
    float* X1 = S + 655360 + 16384;       // 13,107,200 (aliased as dall)
    float* dall = X1;
    unsigned short* pmH  = (unsigned short*)(X1 + 13107200);   // 13.1M bf16
    unsigned short* encH = (unsigned short*)(X1 + 13107200 + 6553600);
    float* pk = X1 + 13107200 + 2 * 6553600;
    float4* aWihP = (float4*)pk;              // 96*768  = 73728 f4
    float4* aWhhP = aWihP + 73728;            // 49152
    float4* w1ihP = aWhhP + 49152;
    float4* w1hhP = w1ihP + 49152;
    float4* w2ihP = w1hhP + 49152;
    float4* w2hhP = w2ihP + 49152;
    float4* pjWP  = w2hhP + 49152;            // 32768
    float4* qWP   = pjWP + 32768;             // 16384

    // zero states + sync area
    hipMemsetAsync(S, 0, (655360 + 16384) * sizeof(float), stream);

    // pack weights [K/4][N] float4
    pack_w<<<64, 256, 0, stream>>>(aWih, aWihP, 768, 384);
    pack_w<<<64, 256, 0, stream>>>(aWhh, aWhhP, 768, 256);
    pack_w<<<64, 256, 0, stream>>>(w1ih, w1ihP, 768, 256);
    pack_w<<<64, 256, 0, stream>>>(w1hh, w1hhP, 768, 256);
    pack_w<<<64, 256, 0, stream>>>(w2ih, w2ihP, 768, 256);
    pack_w<<<64, 256, 0, stream>>>(w2hh, w2hhP, 768, 256);
    pack_w<<<64, 256, 0, stream>>>(pjW,  pjWP,  256, 512);
    pack_w<<<64, 256, 0, stream>>>(qW,   qWP,   256, 256);
    // enc -> bf16
    pack_bf16<<<1024, 256, 0, stream>>>(enc, encH, 13107200);

    // prenet1: X1 = relu(prev @ W1^T + b1)
    gemm128<2, 1><<<dim3(400, 2), 256, 0, stream>>>(
        inputs, 0, pW1, 400, pb1, X1, 256, 51200, 256, 400);
    // prenet2: X2 = relu(X1 @ W2^T + b2)
    gemm128<0, 1><<<dim3(400, 1), 256, 0, stream>>>(
        X1, 256, pW2, 256, pb2, X2, 128, 51200, 128, 256);
    // processed_memory = enc @ memW^T, stored bf16
    gemm128<0, 3><<<dim3(400, 2), 256, 0, stream>>>(
        enc, 256, memW, 256, nullptr, (float*)pmH, 256, 51200, 256, 256);

    // the 200-step sequential decoder (8 independent groups)
    decoder_loop<<<256, 768, 0, stream>>>(
        X2, pmH, encH, mlen,
        aWihP, abih, aWhhP, abhh, qWP, vW, pjWP, pjb,
        w1ihP, w1bih, w1hhP, w1bhh, w2ihP, w2bih, w2hhP, w2bhh,
        ha, h1g, h2g, attb, d0g, d1g, dall, out + ALIGN_OFF, flags, gen);

    // mel projection: out[b,t,:] = dall[t,b,:] @ melW^T + melb
    gemm128<0, 2><<<dim3(400, 4), 256, 0, stream>>>(
        dall, 256, melW, 256, melb, out, 400, 51200, 400, 256);
}

// Round 7
// 13083.301 us; speedup vs baseline: 4.5371x; 3.7348x over previous
//
#include <hip/hip_runtime.h>
#include <math.h>

// B=256, T_ENC=200, D=256, T_MEL=1000, NMEL=80, R=5, IN_R=400, Td=200
#define ALIGN_OFF 20480000   // 256*200*400
#define FLSTRIDE 32          // u32s per flag line (128B padding)
#define BPG 32               // blocks per group (8 groups of 32)

typedef float f32x4 __attribute__((ext_vector_type(4)));

__device__ __forceinline__ float sigf(float x) {
    return __builtin_amdgcn_rcpf(1.0f + __expf(-x));
}
__device__ __forceinline__ float tanhff(float x) {
    float e = __expf(2.0f * x);
    return 1.0f - 2.0f * __builtin_amdgcn_rcpf(e + 1.0f);
}
__device__ __forceinline__ unsigned short f2bf(float x) {
    unsigned u = __float_as_uint(x);
    return (unsigned short)((u + 0x7FFFu + ((u >> 16) & 1u)) >> 16);
}
__device__ __forceinline__ float blo(unsigned u) { return __uint_as_float(u << 16); }
__device__ __forceinline__ float bhi(unsigned u) { return __uint_as_float(u & 0xffff0000u); }

// device-coherent (IC-level) state accessors: bypass L1+L2 so no cache
// invalidation is ever needed for cross-block visibility.
__device__ __forceinline__ f32x4 ld_dev_f4(const float* p) {
    f32x4 r;
    asm volatile("global_load_dwordx4 %0, %1, off sc0 sc1\n\ts_waitcnt vmcnt(0)"
                 : "=&v"(r) : "v"(p) : "memory");
    return r;
}
__device__ __forceinline__ void st_dev_f1(float* p, float v) {
    asm volatile("global_store_dword %0, %1, off sc0 sc1" :: "v"(p), "v"(v) : "memory");
}

// ---------------------------------------------------------------------------
// 128x128-tile fp32 GEMM (prenet / processed_memory / mel) — unchanged.
// ---------------------------------------------------------------------------
template<int AMODE, int EPI>
__global__ __launch_bounds__(256)
void gemm128(const float* __restrict__ A, int lda,
             const float* __restrict__ W, int ldw,
             const float* __restrict__ bias,
             float* __restrict__ C, int ldc, int M, int N, int K)
{
    __shared__ float As[16][128];
    __shared__ float Bs[16][128];
    const int m0 = blockIdx.x * 128, n0 = blockIdx.y * 128;
    const int tid = threadIdx.x;
    const int tx = tid & 15, ty = tid >> 4;
    float acc[8][8] = {};
    for (int k0 = 0; k0 < K; k0 += 16) {
        {
            const int m = tid >> 1, h = (tid & 1) * 8;
            const int grow = m0 + m;
            float4 a0, a1;
            if (AMODE == 2) {
                int t = grow >> 8, b = grow & 255;
                if (t == 0) { a0 = make_float4(0, 0, 0, 0); a1 = a0; }
                else {
                    const float* p = A + (size_t)b * 80000 + (t - 1) * 400 + k0 + h;
                    a0 = *(const float4*)p; a1 = *(const float4*)(p + 4);
                }
            } else {
                const float* p = A + (size_t)grow * lda + k0 + h;
                a0 = *(const float4*)p; a1 = *(const float4*)(p + 4);
            }
            As[h + 0][m] = a0.x; As[h + 1][m] = a0.y; As[h + 2][m] = a0.z; As[h + 3][m] = a0.w;
            As[h + 4][m] = a1.x; As[h + 5][m] = a1.y; As[h + 6][m] = a1.z; As[h + 7][m] = a1.w;
            const int gn = n0 + m;
            float4 b0, b1;
            if (gn < N) {
                const float* p = W + (size_t)gn * ldw + k0 + h;
                b0 = *(const float4*)p; b1 = *(const float4*)(p + 4);
            } else { b0 = make_float4(0, 0, 0, 0); b1 = b0; }
            Bs[h + 0][m] = b0.x; Bs[h + 1][m] = b0.y; Bs[h + 2][m] = b0.z; Bs[h + 3][m] = b0.w;
            Bs[h + 4][m] = b1.x; Bs[h + 5][m] = b1.y; Bs[h + 6][m] = b1.z; Bs[h + 7][m] = b1.w;
        }
        __syncthreads();
        #pragma unroll
        for (int kk = 0; kk < 16; ++kk) {
            float av[8], bv[8];
            *(float4*)&av[0] = *(const float4*)&As[kk][ty * 8];
            *(float4*)&av[4] = *(const float4*)&As[kk][ty * 8 + 4];
            *(float4*)&bv[0] = *(const float4*)&Bs[kk][tx * 8];
            *(float4*)&bv[4] = *(const float4*)&Bs[kk][tx * 8 + 4];
            #pragma unroll
            for (int i = 0; i < 8; ++i)
                #pragma unroll
                for (int j = 0; j < 8; ++j)
                    acc[i][j] += av[i] * bv[j];
        }
        __syncthreads();
    }
    #pragma unroll
    for (int i = 0; i < 8; ++i) {
        const int row = m0 + ty * 8 + i;
        const int t_ = row >> 8, b_ = row & 255;
        #pragma unroll
        for (int j4 = 0; j4 < 2; ++j4) {
            const int col = n0 + tx * 8 + j4 * 4;
            if (col >= N) continue;
            float4 v;
            float* pv = &v.x;
            #pragma unroll
            for (int u = 0; u < 4; ++u) {
                float x = acc[i][j4 * 4 + u] + (bias ? bias[col + u] : 0.0f);
                if (EPI == 1) x = fmaxf(x, 0.0f);
                pv[u] = x;
            }
            if (EPI == 2)      *(float4*)(C + (size_t)b_ * 80000 + t_ * 400 + col) = v;
            else if (EPI == 3) {
                ushort4 o;
                o.x = f2bf(pv[0]); o.y = f2bf(pv[1]); o.z = f2bf(pv[2]); o.w = f2bf(pv[3]);
                *(ushort4*)((unsigned short*)C + (size_t)row * 256 + col) = o;
            } else             *(float4*)(C + (size_t)row * ldc + col) = v;
        }
    }
}

// ---------------------------------------------------------------------------
// Pack W [N][K] -> fp32 [K/4][N] float4
// ---------------------------------------------------------------------------
__global__ __launch_bounds__(256)
void pack_w(const float* __restrict__ W, float4* __restrict__ P, int N, int K)
{
    const int tot = N * (K >> 2);
    for (int i = blockIdx.x * 256 + threadIdx.x; i < tot; i += gridDim.x * 256) {
        const int n = i % N, k4 = i / N;
        P[(size_t)k4 * N + n] = *(const float4*)(W + (size_t)n * K + (k4 << 2));
    }
}

// Pack W [N][K] -> bf16 [K/8][N] ushort8 (as uint4)
__global__ __launch_bounds__(256)
void pack_wb(const float* __restrict__ W, uint4* __restrict__ P, int N, int K)
{
    const int tot = N * (K >> 3);
    for (int i = blockIdx.x * 256 + threadIdx.x; i < tot; i += gridDim.x * 256) {
        const int n = i % N, k8 = i / N;
        const float* s = W + (size_t)n * K + (k8 << 3);
        uint4 o;
        o.x = (unsigned)f2bf(s[0]) | ((unsigned)f2bf(s[1]) << 16);
        o.y = (unsigned)f2bf(s[2]) | ((unsigned)f2bf(s[3]) << 16);
        o.z = (unsigned)f2bf(s[4]) | ((unsigned)f2bf(s[5]) << 16);
        o.w = (unsigned)f2bf(s[6]) | ((unsigned)f2bf(s[7]) << 16);
        P[(size_t)k8 * N + n] = o;
    }
}

// fp32 -> bf16 elementwise pack
__global__ __launch_bounds__(256)
void pack_bf16(const float* __restrict__ src, unsigned short* __restrict__ dst, int n)
{
    for (int i = (blockIdx.x * 256 + threadIdx.x) * 4; i < n; i += gridDim.x * 1024) {
        float4 v = *(const float4*)(src + i);
        ushort4 o;
        o.x = f2bf(v.x); o.y = f2bf(v.y); o.z = f2bf(v.z); o.w = f2bf(v.w);
        *(ushort4*)(dst + i) = o;
    }
}

// ---------------------------------------------------------------------------
// Per-group barrier: relaxed flags only, NO fences, NO cache invalidation.
// Cross-block data correctness comes from the sc0/sc1 state plane.
// __syncthreads() drains each block's vmem (compiler emits waitcnt) before
// the flag store, so sc1 state writes are at the coherence point first.
// ---------------------------------------------------------------------------
__device__ __forceinline__ void gsync(unsigned* flags, unsigned* gen,
                                      unsigned target, int g, int j, int tid)
{
    __syncthreads();
    if (j == 0) {
        if (tid >= 1 && tid < BPG) {
            const unsigned* f = flags + (size_t)(g * BPG + tid) * FLSTRIDE;
            while (__hip_atomic_load(f, __ATOMIC_RELAXED, __HIP_MEMORY_SCOPE_AGENT) < target)
                __builtin_amdgcn_s_sleep(1);
        }
        __syncthreads();
        if (tid == 0) {
            asm volatile("s_waitcnt vmcnt(0)" ::: "memory");
            __hip_atomic_store(gen + (size_t)g * FLSTRIDE, target, __ATOMIC_RELAXED, __HIP_MEMORY_SCOPE_AGENT);
        }
    } else {
        if (tid == 0) {
            asm volatile("s_waitcnt vmcnt(0)" ::: "memory");
            __hip_atomic_store(flags + (size_t)(g * BPG + j) * FLSTRIDE, target, __ATOMIC_RELAXED, __HIP_MEMORY_SCOPE_AGENT);
            const unsigned* gp = gen + (size_t)g * FLSTRIDE;
            while (__hip_atomic_load(gp, __ATOMIC_RELAXED, __HIP_MEMORY_SCOPE_AGENT) < target)
                __builtin_amdgcn_s_sleep(1);
        }
    }
    __syncthreads();
}

// ---------------------------------------------------------------------------
// GRU phase: 4 rows x 64 gate-cols per block, one gate per thread-third.
// Weights bf16 k8-packed [K/8][768] (L2-resident, coalesced 1KB/wave reads).
// State in/out through the device-coherent (sc0 sc1) plane.
// ---------------------------------------------------------------------------
template<int KX, bool CONCAT>
__device__ __forceinline__ void gru3(
    float* smem, int r0, int c0, int tid,
    const float* __restrict__ xA,      // CONCAT: X2 slice (cached); else state
    const float* __restrict__ xB,      // CONCAT: attention state
    const float* __restrict__ hbuf,    // state
    const uint4* __restrict__ WihB, const float* __restrict__ bih,
    const uint4* __restrict__ WhhB, const float* __restrict__ bhh,
    float* __restrict__ hout, float* __restrict__ res1)
{
    __syncthreads();   // protect smem reuse across unbarriered phase boundary
    constexpr int XW = KX / 4;            // float4s per row
    f32x4* xs = (f32x4*)smem;             // [4][XW]
    f32x4* hs = xs + 4 * XW;              // [4][64]
    float* pi_ = (float*)(hs + 256);      // [3][256]
    float* ph_ = pi_ + 768;               // [3][256]
    if (CONCAT) {
        if (tid < 4 * XW) {
            const int r = tid / XW, k = tid % XW;
            xs[tid] = (k < 32)
                ? *(const f32x4*)(xA + (size_t)(r0 + r) * 128 + k * 4)
                : ld_dev_f4(xB + (size_t)(r0 + r) * 256 + (k - 32) * 4);
        }
    } else {
        if (tid < 4 * XW) {
            const int r = tid >> 6, k = tid & 63;
            xs[tid] = ld_dev_f4(xA + (size_t)(r0 + r) * 256 + k * 4);
        }
    }
    if (tid < 256) {
        hs[tid] = ld_dev_f4(hbuf + (size_t)(r0 + (tid >> 6)) * 256 + (tid & 63) * 4);
    }
    __syncthreads();
    {
        const int g = tid >> 8, idx = tid & 255;
        const int r4 = idx >> 6, cl = idx & 63;
        const int n = (g << 8) + c0 + cl;
        float ai = 0.f, ah = 0.f;
        const f32x4* xr = xs + r4 * XW;
        const uint4* wp = WihB + n;
        #pragma unroll 8
        for (int k8 = 0; k8 < KX / 8; ++k8) {
            const uint4 w = wp[(size_t)k8 * 768];
            const f32x4 a0 = xr[2 * k8], a1 = xr[2 * k8 + 1];
            ai += a0.x * blo(w.x) + a0.y * bhi(w.x) + a0.z * blo(w.y) + a0.w * bhi(w.y);
            ai += a1.x * blo(w.z) + a1.y * bhi(w.z) + a1.z * blo(w.w) + a1.w * bhi(w.w);
        }
        const f32x4* hr = hs + r4 * 64;
        const uint4* wq = WhhB + n;
        #pragma unroll 8
        for (int k8 = 0; k8 < 32; ++k8) {
            const uint4 w = wq[(size_t)k8 * 768];
            const f32x4 a0 = hr[2 * k8], a1 = hr[2 * k8 + 1];
            ah += a0.x * blo(w.x) + a0.y * bhi(w.x) + a0.z * blo(w.y) + a0.w * bhi(w.y);
            ah += a1.x * blo(w.z) + a1.y * bhi(w.z) + a1.z * blo(w.w) + a1.w * bhi(w.w);
        }
        pi_[(g << 8) + idx] = ai + bih[n];
        ph_[(g << 8) + idx] = ah + bhh[n];
    }
    __syncthreads();
    if (tid < 256) {
        const int r4 = tid >> 6, cl = tid & 63;
        const int col = c0 + cl, row = r0 + r4;
        const float vr = sigf(pi_[tid] + ph_[tid]);
        const float vz = sigf(pi_[256 + tid] + ph_[256 + tid]);
        const float vn = tanhff(pi_[512 + tid] + vr * ph_[512 + tid]);
        const float hold = ((const float*)hs)[r4 * 256 + col];
        const float hp = (1.f - vz) * vn + vz * hold;
        st_dev_f1(hout + (size_t)row * 256 + col, hp);
        if (res1) st_dev_f1(res1 + (size_t)row * 256 + col,
                            hp + ((const float*)xs)[r4 * KX + col]);
    }
}

// ---------------------------------------------------------------------------
// Persistent decoder: 8 groups of 32 blocks; enc row LDS-resident; pm via
// non-temporal loads; weights bf16 L2-resident; state via sc0/sc1 plane.
// ---------------------------------------------------------------------------
__global__ __launch_bounds__(768)
void decoder_loop(
    const float* __restrict__ X2,            // [200][256][128] fp32
    const unsigned short* __restrict__ pmH,  // [256][200][256] bf16
    const unsigned short* __restrict__ encH, // [256][200][256] bf16
    const int*   __restrict__ mlen,
    const uint4* __restrict__ aWihB, const float* __restrict__ abih,
    const uint4* __restrict__ aWhhB, const float* __restrict__ abhh,
    const float4* __restrict__ qWP,  const float* __restrict__ vW,
    const float4* __restrict__ pjWP, const float* __restrict__ pjb,
    const uint4* __restrict__ w1ihB, const float* __restrict__ w1bih,
    const uint4* __restrict__ w1hhB, const float* __restrict__ w1bhh,
    const uint4* __restrict__ w2ihB, const float* __restrict__ w2bih,
    const uint4* __restrict__ w2hhB, const float* __restrict__ w2bhh,
    float* __restrict__ ha,   float* __restrict__ h1g, float* __restrict__ h2g,
    float* __restrict__ attb, float* __restrict__ d0g, float* __restrict__ d1g,
    float* __restrict__ dall, float* __restrict__ alout,
    unsigned* __restrict__ flags, unsigned* __restrict__ gen)
{
    __shared__ unsigned short encS[51200];   // this block's enc row, bf16
    __shared__ float work[4608];
    __shared__ float vvS[256];
    const int bid = blockIdx.x, tid = threadIdx.x;
    const int g = bid & 7, j = bid >> 3;
    const int rowbase = g * 32;
    const int jr = j >> 2, jc = j & 3;
    const int r0 = rowbase + jr * 4, c0 = jc * 64;
    const int batt = rowbase + j;            // this block's P2 batch row
    unsigned bt = 0;

    // one-time: enc row -> LDS (102,400 B), v weights -> LDS
    {
        const uint4* esrc = (const uint4*)(encH + (size_t)batt * 51200);
        uint4* edst = (uint4*)encS;
        for (int i = tid; i < 6400; i += 768) edst[i] = esrc[i];
        if (tid < 256) vvS[tid] = vW[tid];
    }
    __syncthreads();

    for (int t = 0; t < 200; ++t) {
        const int pi = t & 1, po = pi ^ 1;
        const float* attP = attb + pi * 65536;
        float* attN = attb + po * 65536;
        const float* hnew = ha + po * 65536;

        // ---- P1: attention GRU: h_a' = GRU([x2_t | att], h_a) ----
        gru3<384, true>(work, r0, c0, tid,
            X2 + (size_t)t * 32768, attP, ha + pi * 65536,
            aWihB, abih, aWhhB, abhh, ha + po * 65536, nullptr);
        gsync(flags, gen, ++bt, g, j, tid);

        // ---- P2: Bahdanau attention (block = one batch row) ----
        {
            float* hv = work;          // 256
            float* qv = hv + 256;      // 256
            float* sc = qv + 256;      // 208
            float* al = sc + 208;      // 208
            float* part = al + 208;    // [12][256] = 3072  (total 4000 < 4608)
            const int b = batt;
            __syncthreads();           // smem reuse guard
            if (tid < 64) *(f32x4*)&hv[tid * 4] = ld_dev_f4(hnew + (size_t)b * 256 + tid * 4);
            __syncthreads();
            if (tid < 256) {
                const float4* h4 = (const float4*)hv;
                const float4* qp = qWP + tid;
                float s = 0.f;
                #pragma unroll 8
                for (int k = 0; k < 64; ++k) {
                    const float4 a = h4[k];
                    const float4 w = qp[(size_t)k * 256];
                    s += a.x * w.x + a.y * w.y + a.z * w.z + a.w * w.w;
                }
                qv[tid] = s;
            }
            __syncthreads();
            const int wv = tid >> 6, ln = tid & 63;
            const int len = mlen[b];
            {
                const float4 q4 = ((const float4*)qv)[ln];
                const float4 v4 = ((const float4*)vvS)[ln];
                #pragma unroll 2
                for (int i = wv; i < 200; i += 12) {
                    const unsigned long long pr = __builtin_nontemporal_load(
                        (const unsigned long long*)(pmH + ((size_t)b * 200 + i) * 256 + ln * 4));
                    const unsigned plo = (unsigned)pr, phi = (unsigned)(pr >> 32);
                    float p = v4.x * tanhff(blo(plo) + q4.x)
                            + v4.y * tanhff(bhi(plo) + q4.y)
                            + v4.z * tanhff(blo(phi) + q4.z)
                            + v4.w * tanhff(bhi(phi) + q4.w);
                    #pragma unroll
                    for (int off = 32; off; off >>= 1) p += __shfl_down(p, off);
                    if (ln == 0) sc[i] = (i < len) ? p : -1e9f;
                }
            }
            __syncthreads();
            if (wv == 0) {
                float v0 = sc[ln], v1 = sc[ln + 64], v2 = sc[ln + 128];
                float v3 = (ln < 8) ? sc[ln + 192] : -1e30f;
                float mx = fmaxf(fmaxf(v0, v1), fmaxf(v2, v3));
                #pragma unroll
                for (int off = 32; off; off >>= 1) mx = fmaxf(mx, __shfl_xor(mx, off));
                float e0 = __expf(v0 - mx), e1 = __expf(v1 - mx), e2 = __expf(v2 - mx);
                float e3 = (ln < 8) ? __expf(v3 - mx) : 0.f;
                float ss = e0 + e1 + e2 + e3;
                #pragma unroll
                for (int off = 32; off; off >>= 1) ss += __shfl_xor(ss, off);
                float inv = 1.0f / ss;
                float* ao = alout + (size_t)b * 40000 + (size_t)t * 200;
                al[ln]       = e0 * inv; ao[ln]       = e0 * inv;
                al[ln + 64]  = e1 * inv; ao[ln + 64]  = e1 * inv;
                al[ln + 128] = e2 * inv; ao[ln + 128] = e2 * inv;
                if (ln < 8) { al[ln + 192] = e3 * inv; ao[ln + 192] = e3 * inv; }
            }
            __syncthreads();
            {
                float a0 = 0.f, a1 = 0.f, a2 = 0.f, a3 = 0.f;
                #pragma unroll 2
                for (int i = wv; i < 200; i += 12) {
                    const float w = al[i];
                    const uint2 ev = *(const uint2*)(encS + i * 256 + ln * 4);
                    a0 = fmaf(w, blo(ev.x), a0);
                    a1 = fmaf(w, bhi(ev.x), a1);
                    a2 = fmaf(w, blo(ev.y), a2);
                    a3 = fmaf(w, bhi(ev.y), a3);
                }
                ((float4*)part)[wv * 64 + ln] = make_float4(a0, a1, a2, a3);
            }
            __syncthreads();
            if (tid < 256) {
                float s = 0.f;
                #pragma unroll
                for (int w2 = 0; w2 < 12; ++w2) s += part[w2 * 256 + tid];
                st_dev_f1(attN + (size_t)b * 256 + tid, s);
            }
        }
        gsync(flags, gen, ++bt, g, j, tid);

        // ---- P3: d0 = [h_a' | att'] @ pjW^T + pjb (split-K by 2) ----
        {
            f32x4* xs = (f32x4*)work;              // [4][128]
            float* part = (float*)(xs + 512);      // [2][256]
            __syncthreads();                       // smem reuse guard
            if (tid < 512) {
                const int r = tid >> 7, k = tid & 127;
                xs[tid] = (k < 64)
                    ? ld_dev_f4(hnew + (size_t)(r0 + r) * 256 + k * 4)
                    : ld_dev_f4(attN + (size_t)(r0 + r) * 256 + (k - 64) * 4);
            }
            __syncthreads();
            if (tid < 512) {
                const int half = tid >> 8, idx = tid & 255;
                const int r4 = idx >> 6, cl = idx & 63;
                const f32x4* xr = xs + r4 * 128 + half * 64;
                const float4* wp = pjWP + (size_t)half * 64 * 256 + c0 + cl;
                float s = 0.f;
                #pragma unroll 8
                for (int k = 0; k < 64; ++k) {
                    const f32x4 a = xr[k];
                    const float4 w = wp[(size_t)k * 256];
                    s += a.x * w.x + a.y * w.y + a.z * w.z + a.w * w.w;
                }
                part[(half << 8) + idx] = s;
            }
            __syncthreads();
            if (tid < 256) {
                const int r4 = tid >> 6, cl = tid & 63;
                st_dev_f1(d0g + (size_t)(r0 + r4) * 256 + c0 + cl,
                          part[tid] + part[256 + tid] + pjb[c0 + cl]);
            }
        }
        gsync(flags, gen, ++bt, g, j, tid);

        // ---- P4: dec1 GRU + residual: d1 = h1' + d0 ----
        gru3<256, false>(work, r0, c0, tid,
            d0g, nullptr, h1g + pi * 65536,
            w1ihB, w1bih, w1hhB, w1bhh, h1g + po * 65536, d1g);
        gsync(flags, gen, ++bt, g, j, tid);

        // ---- P5: dec2 GRU + residual -> dall[t] ----
        gru3<256, false>(work, r0, c0, tid,
            d1g, nullptr, h2g + pi * 65536,
            w2ihB, w2bih, w2hhB, w2bhh, h2g + po * 65536,
            dall + (size_t)t * 65536);
        // no group barrier: consumers >=4 barriers away; block-local smem
        // hazard covered by __syncthreads at gru3/P2 entry
    }
}

// ---------------------------------------------------------------------------
extern "C" void kernel_launch(void* const* d_in, const int* in_sizes, int n_in,
                              void* d_out, int out_size, void* d_ws, size_t ws_size,
                              hipStream_t stream)
{
    const float* enc    = (const float*)d_in[0];
    const float* inputs = (const float*)d_in[1];
    const int*   mlen   = (const int*)d_in[2];
    const float* pW1 = (const float*)d_in[3];  const float* pb1 = (const float*)d_in[4];
    const float* pW2 = (const float*)d_in[5];  const float* pb2 = (const float*)d_in[6];
    const float* aWih = (const float*)d_in[7]; const float* abih = (const float*)d_in[8];
    const float* aWhh = (const float*)d_in[9]; const float* abhh = (const float*)d_in[10];
    const float* memW = (const float*)d_in[11];
    const float* qW   = (const float*)d_in[12];
    const float* vW   = (const float*)d_in[13];
    const float* pjW  = (const float*)d_in[14]; const float* pjb = (const float*)d_in[15];
    const float* w1ih = (const float*)d_in[16]; const float* w1bih = (const float*)d_in[17];
    const float* w1hh = (const float*)d_in[18]; const float* w1bhh = (const float*)d_in[19];
    const float* w2ih = (const float*)d_in[20]; const float* w2bih = (const float*)d_in[21];
    const float* w2hh = (const float*)d_in[22]; const float* w2bhh = (const float*)d_in[23];
    const float* melW = (const float*)d_in[24]; const float* melb = (const float*)d_in[25];

    float* out = (float*)d_out;
    float* ws  = (float*)d_ws;

    // workspace layout (floats)
    float* X2 = ws;                       // 6,553,600
    float* S  = X2 + 6553600;             // 10 x 65536 states
    float* ha   = S;
    float* h1g  = S + 2 * 65536;
    float* h2g  = S + 4 * 65536;
    float* attb = S + 6 * 65536;
    float* d0g  = S + 8 * 65536;
    float* d1g  = S + 9 * 65536;
    unsigned* flags = (unsigned*)(S + 655360);   // 8192 u32
    unsigned* gen   = flags + 8192;              // within 16384-float pad
    float* X1 = S + 655360 + 16384;       // 13,107,200 (aliased as dall)
    float* dall = X1;
    unsigned short* pmH  = (unsigned short*)(X1 + 13107200);   // 26 MB bf16
    unsigned short* encH = (unsigned short*)(X1 + 13107200 + 6553600);
    float* pk = X1 + 13107200 + 2 * 6553600;
    uint4* aWihB = (uint4*)pk;                    // 768*384/8 = 36864 uint4
    uint4* aWhhB = aWihB + 36864;                 // 768*256/8 = 24576
    uint4* w1ihB = aWhhB + 24576;
    uint4* w1hhB = w1ihB + 24576;
    uint4* w2ihB = w1hhB + 24576;
    uint4* w2hhB = w2ihB + 24576;
    float4* pjWP = (float4*)(w2hhB + 24576);      // 128*256 = 32768 f4
    float4* qWP  = pjWP + 32768;                  // 64*256  = 16384 f4

    // zero states + sync area
    hipMemsetAsync(S, 0, (655360 + 16384) * sizeof(float), stream);

    // pack weights
    pack_wb<<<64, 256, 0, stream>>>(aWih, aWihB, 768, 384);
    pack_wb<<<64, 256, 0, stream>>>(aWhh, aWhhB, 768, 256);
    pack_wb<<<64, 256, 0, stream>>>(w1ih, w1ihB, 768, 256);
    pack_wb<<<64, 256, 0, stream>>>(w1hh, w1hhB, 768, 256);
    pack_wb<<<64, 256, 0, stream>>>(w2ih, w2ihB, 768, 256);
    pack_wb<<<64, 256, 0, stream>>>(w2hh, w2hhB, 768, 256);
    pack_w<<<64, 256, 0, stream>>>(pjW, pjWP, 256, 512);
    pack_w<<<64, 256, 0, stream>>>(qW,  qWP,  256, 256);
    pack_bf16<<<1024, 256, 0, stream>>>(enc, encH, 13107200);

    // prenet1: X1 = relu(prev @ W1^T + b1)
    gemm128<2, 1><<<dim3(400, 2), 256, 0, stream>>>(
        inputs, 0, pW1, 400, pb1, X1, 256, 51200, 256, 400);
    // prenet2: X2 = relu(X1 @ W2^T + b2)
    gemm128<0, 1><<<dim3(400, 1), 256, 0, stream>>>(
        X1, 256, pW2, 256, pb2, X2, 128, 51200, 128, 256);
    // processed_memory = enc @ memW^T, stored bf16
    gemm128<0, 3><<<dim3(400, 2), 256, 0, stream>>>(
        enc, 256, memW, 256, nullptr, (float*)pmH, 256, 51200, 256, 256);

    // the 200-step sequential decoder
    decoder_loop<<<256, 768, 0, stream>>>(
        X2, pmH, encH, mlen,
        aWihB, abih, aWhhB, abhh, qWP, vW, pjWP, pjb,
        w1ihB, w1bih, w1hhB, w1bhh, w2ihB, w2bih, w2hhB, w2bhh,
        ha, h1g, h2g, attb, d0g, d1g, dall, out + ALIGN_OFF, flags, gen);

    // mel projection: out[b,t,:] = dall[t,b,:] @ melW^T + melb
    gemm128<0, 2><<<dim3(400, 4), 256, 0, stream>>>(
        dall, 256, melW, 256, melb, out, 400, 51200, 400, 256);
}

// Round 9
// 8206.016 us; speedup vs baseline: 7.2337x; 1.5944x over previous
//
#include <hip/hip_runtime.h>
#include <math.h>

// B=256, T_ENC=200, D=256, T_MEL=1000, NMEL=80, R=5, IN_R=400, Td=200
#define ALIGN_OFF 20480000   // 256*200*400

typedef __fp16 h2_t __attribute__((ext_vector_type(2)));

__device__ __forceinline__ float sigf(float x) {
    return __builtin_amdgcn_rcpf(1.0f + __expf(-x));
}
__device__ __forceinline__ float tanhff(float x) {
    float e = __expf(2.0f * x);
    return 1.0f - 2.0f * __builtin_amdgcn_rcpf(e + 1.0f);
}
__device__ __forceinline__ unsigned short f2bf(float x) {
    unsigned u = __float_as_uint(x);
    return (unsigned short)((u + 0x7FFFu + ((u >> 16) & 1u)) >> 16);
}
__device__ __forceinline__ float blo(unsigned u) { return __uint_as_float(u << 16); }
__device__ __forceinline__ float bhi(unsigned u) { return __uint_as_float(u & 0xffff0000u); }
// pack two f32 -> f16x2 (RTZ)
__device__ __forceinline__ unsigned pkh(float a, float b) {
    h2_t r = __builtin_amdgcn_cvt_pkrtz(a, b);
    return __builtin_bit_cast(unsigned, r);
}
// f16 pair dot with f32 accumulate: c += a.x*b.x + a.y*b.y
__device__ __forceinline__ float dot2(unsigned w, unsigned a, float c) {
#if __has_builtin(__builtin_amdgcn_fdot2)
    return __builtin_amdgcn_fdot2(__builtin_bit_cast(h2_t, w),
                                  __builtin_bit_cast(h2_t, a), c, false);
#else
    h2_t wv = __builtin_bit_cast(h2_t, w), av = __builtin_bit_cast(h2_t, a);
    return c + (float)wv.x * (float)av.x + (float)wv.y * (float)av.y;
#endif
}

// ---------------------------------------------------------------------------
// 128x128-tile fp32 GEMM (prenet / processed_memory / mel).
// AMODE: 0 plain; 2 teacher-forcing virtual A (prenet1)
// EPI: 0 plain, 1 relu, 2 mel-layout store, 3 bf16 store (ld 256),
//      4 relu + f16 store (ld 128 halves = 64 uints)
// ---------------------------------------------------------------------------
template<int AMODE, int EPI>
__global__ __launch_bounds__(256)
void gemm128(const float* __restrict__ A, int lda,
             const float* __restrict__ W, int ldw,
             const float* __restrict__ bias,
             float* __restrict__ C, int ldc, int M, int N, int K)
{
    __shared__ float As[16][128];
    __shared__ float Bs[16][128];
    const int m0 = blockIdx.x * 128, n0 = blockIdx.y * 128;
    const int tid = threadIdx.x;
    const int tx = tid & 15, ty = tid >> 4;
    float acc[8][8] = {};
    for (int k0 = 0; k0 < K; k0 += 16) {
        {
            const int m = tid >> 1, h = (tid & 1) * 8;
            const int grow = m0 + m;
            float4 a0, a1;
            if (AMODE == 2) {
                int t = grow >> 8, b = grow & 255;
                if (t == 0) { a0 = make_float4(0, 0, 0, 0); a1 = a0; }
                else {
                    const float* p = A + (size_t)b * 80000 + (t - 1) * 400 + k0 + h;
                    a0 = *(const float4*)p; a1 = *(const float4*)(p + 4);
                }
            } else {
                const float* p = A + (size_t)grow * lda + k0 + h;
                a0 = *(const float4*)p; a1 = *(const float4*)(p + 4);
            }
            As[h + 0][m] = a0.x; As[h + 1][m] = a0.y; As[h + 2][m] = a0.z; As[h + 3][m] = a0.w;
            As[h + 4][m] = a1.x; As[h + 5][m] = a1.y; As[h + 6][m] = a1.z; As[h + 7][m] = a1.w;
            const int gn = n0 + m;
            float4 b0, b1;
            if (gn < N) {
                const float* p = W + (size_t)gn * ldw + k0 + h;
                b0 = *(const float4*)p; b1 = *(const float4*)(p + 4);
            } else { b0 = make_float4(0, 0, 0, 0); b1 = b0; }
            Bs[h + 0][m] = b0.x; Bs[h + 1][m] = b0.y; Bs[h + 2][m] = b0.z; Bs[h + 3][m] = b0.w;
            Bs[h + 4][m] = b1.x; Bs[h + 5][m] = b1.y; Bs[h + 6][m] = b1.z; Bs[h + 7][m] = b1.w;
        }
        __syncthreads();
        #pragma unroll
        for (int kk = 0; kk < 16; ++kk) {
            float av[8], bv[8];
            *(float4*)&av[0] = *(const float4*)&As[kk][ty * 8];
            *(float4*)&av[4] = *(const float4*)&As[kk][ty * 8 + 4];
            *(float4*)&bv[0] = *(const float4*)&Bs[kk][tx * 8];
            *(float4*)&bv[4] = *(const float4*)&Bs[kk][tx * 8 + 4];
            #pragma unroll
            for (int i = 0; i < 8; ++i)
                #pragma unroll
                for (int j = 0; j < 8; ++j)
                    acc[i][j] += av[i] * bv[j];
        }
        __syncthreads();
    }
    #pragma unroll
    for (int i = 0; i < 8; ++i) {
        const int row = m0 + ty * 8 + i;
        const int t_ = row >> 8, b_ = row & 255;
        #pragma unroll
        for (int j4 = 0; j4 < 2; ++j4) {
            const int col = n0 + tx * 8 + j4 * 4;
            if (col >= N) continue;
            float4 v;
            float* pv = &v.x;
            #pragma unroll
            for (int u = 0; u < 4; ++u) {
                float x = acc[i][j4 * 4 + u] + (bias ? bias[col + u] : 0.0f);
                if (EPI == 1 || EPI == 4) x = fmaxf(x, 0.0f);
                pv[u] = x;
            }
            if (EPI == 2)      *(float4*)(C + (size_t)b_ * 80000 + t_ * 400 + col) = v;
            else if (EPI == 3) {
                ushort4 o;
                o.x = f2bf(pv[0]); o.y = f2bf(pv[1]); o.z = f2bf(pv[2]); o.w = f2bf(pv[3]);
                *(ushort4*)((unsigned short*)C + (size_t)row * 256 + col) = o;
            } else if (EPI == 4) {
                uint2 o; o.x = pkh(pv[0], pv[1]); o.y = pkh(pv[2], pv[3]);
                *(uint2*)((unsigned*)C + (size_t)row * 64 + (col >> 1)) = o;
            } else *(float4*)(C + (size_t)row * ldc + col) = v;
        }
    }
}

// ---------------------------------------------------------------------------
// Pack W [N][K] f32 -> f16 [K/8][N] uint4 (8 halves per entry).
// ---------------------------------------------------------------------------
__global__ __launch_bounds__(256)
void pack_wh(const float* __restrict__ W, uint4* __restrict__ P, int N, int K)
{
    const int tot = N * (K >> 3);
    for (int i = blockIdx.x * 256 + threadIdx.x; i < tot; i += gridDim.x * 256) {
        const int n = i % N, k8 = i / N;
        const float* s = W + (size_t)n * K + (k8 << 3);
        uint4 o;
        o.x = pkh(s[0], s[1]); o.y = pkh(s[2], s[3]);
        o.z = pkh(s[4], s[5]); o.w = pkh(s[6], s[7]);
        P[(size_t)k8 * N + n] = o;
    }
}

// fp32 -> bf16 elementwise pack
__global__ __launch_bounds__(256)
void pack_bf16(const float* __restrict__ src, unsigned short* __restrict__ dst, int n)
{
    for (int i = (blockIdx.x * 256 + threadIdx.x) * 4; i < n; i += gridDim.x * 1024) {
        float4 v = *(const float4*)(src + i);
        ushort4 o;
        o.x = f2bf(v.x); o.y = f2bf(v.y); o.z = f2bf(v.z); o.w = f2bf(v.w);
        *(ushort4*)(dst + i) = o;
    }
}

// ---------------------------------------------------------------------------
// Zero-barrier persistent decoder: block b owns batch row b completely.
// All recurrent state lives in LDS; 768 threads = 768 gate columns; weights
// f16 [K/8][N] uint4, read coalesced from L2; dots via v_dot2_f32_f16.
// ---------------------------------------------------------------------------
__global__ __launch_bounds__(768)
void decoder_loop(
    const uint4* __restrict__ X2h4,          // [200*256][16] uint4, f16 prenet out
    const unsigned short* __restrict__ pmH,  // [256][200][256] bf16
    const unsigned short* __restrict__ encH, // [256][200][256] bf16
    const int*   __restrict__ mlen,
    const uint4* __restrict__ aWihH, const float* __restrict__ abih,
    const uint4* __restrict__ aWhhH, const float* __restrict__ abhh,
    const uint4* __restrict__ qWH,   const float* __restrict__ vW,
    const uint4* __restrict__ pjWH,  const float* __restrict__ pjb,
    const uint4* __restrict__ w1ihH, const float* __restrict__ w1bih,
    const uint4* __restrict__ w1hhH, const float* __restrict__ w1bhh,
    const uint4* __restrict__ w2ihH, const float* __restrict__ w2bih,
    const uint4* __restrict__ w2hhH, const float* __restrict__ w2bhh,
    float* __restrict__ dall, float* __restrict__ alout)
{
    __shared__ unsigned short encS[51200];   // this row's enc, bf16 (100 KB)
    __shared__ uint4 xcat[48];               // f16 [x2_t (16) | att (32)]
    __shared__ unsigned ha_h[128], h1_h[128], h2_h[128], d0_h[128], d1_h[128];
    __shared__ float hA[256], h1s[256], h2s[256], d0s[256], d1s[256];
    __shared__ float qv[256], vvS[256];
    __shared__ float sc[200], al[208];
    __shared__ float gi[768], gh[768];
    __shared__ float part[12][256];

    const int b = blockIdx.x, tid = threadIdx.x;
    const int wv = tid >> 6, ln = tid & 63;

    // one-time init
    {
        const uint4* esrc = (const uint4*)(encH + (size_t)b * 51200);
        for (int i = tid; i < 6400; i += 768) ((uint4*)encS)[i] = esrc[i];
        if (tid < 256) { vvS[tid] = vW[tid]; hA[tid] = 0.f; h1s[tid] = 0.f; h2s[tid] = 0.f; }
        if (tid < 128) { ha_h[tid] = 0u; h1_h[tid] = 0u; h2_h[tid] = 0u; }
        if (tid < 32)  xcat[16 + tid] = make_uint4(0, 0, 0, 0);   // att = 0
    }
    const int len = mlen[b];
    __syncthreads();

    for (int t = 0; t < 200; ++t) {
        // ---- P1: attention GRU  h_a' = GRU([x2_t | att], h_a) ----
        if (tid < 16) xcat[tid] = X2h4[((size_t)t * 256 + b) * 16 + tid];
        __syncthreads();
        {
            float ai = 0.f, ah = 0.f;
            const uint4* wp = aWihH + tid;
            #pragma unroll 8
            for (int k8 = 0; k8 < 48; ++k8) {
                const uint4 w = wp[(size_t)k8 * 768], a = xcat[k8];
                ai = dot2(w.x, a.x, ai); ai = dot2(w.y, a.y, ai);
                ai = dot2(w.z, a.z, ai); ai = dot2(w.w, a.w, ai);
            }
            const uint4* wq = aWhhH + tid;
            const uint4* hc = (const uint4*)ha_h;
            #pragma unroll 8
            for (int k8 = 0; k8 < 32; ++k8) {
                const uint4 w = wq[(size_t)k8 * 768], a = hc[k8];
                ah = dot2(w.x, a.x, ah); ah = dot2(w.y, a.y, ah);
                ah = dot2(w.z, a.z, ah); ah = dot2(w.w, a.w, ah);
            }
            gi[tid] = ai + abih[tid];
            gh[tid] = ah + abhh[tid];
        }
        __syncthreads();
        if (tid < 256) {
            const float r = sigf(gi[tid] + gh[tid]);
            const float z = sigf(gi[256 + tid] + gh[256 + tid]);
            const float n = tanhff(gi[512 + tid] + r * gh[512 + tid]);
            const float hp = (1.f - z) * n + z * hA[tid];
            hA[tid] = hp;
            const float hq = __shfl_down(hp, 1);
            if (!(tid & 1)) ha_h[tid >> 1] = pkh(hp, hq);
        }
        __syncthreads();

        // ---- P2: q = h_a' @ qW^T ----
        if (tid < 256) {
            float s = 0.f;
            const uint4* qp = qWH + tid;
            const uint4* hc = (const uint4*)ha_h;
            #pragma unroll 8
            for (int k8 = 0; k8 < 32; ++k8) {
                const uint4 w = qp[(size_t)k8 * 256], a = hc[k8];
                s = dot2(w.x, a.x, s); s = dot2(w.y, a.y, s);
                s = dot2(w.z, a.z, s); s = dot2(w.w, a.w, s);
            }
            qv[tid] = s;
        }
        __syncthreads();
        // ---- scores: sc[i] = v . tanh(pm[i] + q), masked ----
        {
            const float4 q4 = ((const float4*)qv)[ln];
            const float4 v4 = ((const float4*)vvS)[ln];
            for (int i = wv; i < 200; i += 12) {
                const unsigned long long pr = __builtin_nontemporal_load(
                    (const unsigned long long*)(pmH + ((size_t)b * 200 + i) * 256 + ln * 4));
                const unsigned plo = (unsigned)pr, phi = (unsigned)(pr >> 32);
                float p = v4.x * tanhff(blo(plo) + q4.x)
                        + v4.y * tanhff(bhi(plo) + q4.y)
                        + v4.z * tanhff(blo(phi) + q4.z)
                        + v4.w * tanhff(bhi(phi) + q4.w);
                #pragma unroll
                for (int off = 32; off; off >>= 1) p += __shfl_down(p, off);
                if (ln == 0) sc[i] = (i < len) ? p : -1e9f;
            }
        }
        __syncthreads();
        if (wv == 0) {
            float v0 = sc[ln], v1 = sc[ln + 64], v2 = sc[ln + 128];
            float v3 = (ln < 8) ? sc[ln + 192] : -1e30f;
            float mx = fmaxf(fmaxf(v0, v1), fmaxf(v2, v3));
            #pragma unroll
            for (int off = 32; off; off >>= 1) mx = fmaxf(mx, __shfl_xor(mx, off));
            float e0 = __expf(v0 - mx), e1 = __expf(v1 - mx), e2 = __expf(v2 - mx);
            float e3 = (ln < 8) ? __expf(v3 - mx) : 0.f;
            float ss = e0 + e1 + e2 + e3;
            #pragma unroll
            for (int off = 32; off; off >>= 1) ss += __shfl_xor(ss, off);
            const float inv = 1.0f / ss;
            float* ao = alout + (size_t)b * 40000 + (size_t)t * 200;
            al[ln]       = e0 * inv; ao[ln]       = e0 * inv;
            al[ln + 64]  = e1 * inv; ao[ln + 64]  = e1 * inv;
            al[ln + 128] = e2 * inv; ao[ln + 128] = e2 * inv;
            if (ln < 8) { al[ln + 192] = e3 * inv; ao[ln + 192] = e3 * inv; }
        }
        __syncthreads();
        // ---- context: att = align @ enc (enc in LDS) ----
        {
            float a0 = 0.f, a1 = 0.f, a2 = 0.f, a3 = 0.f;
            for (int i = wv; i < 200; i += 12) {
                const float w = al[i];
                const uint2 ev = *(const uint2*)(encS + i * 256 + ln * 4);
                a0 = fmaf(w, blo(ev.x), a0); a1 = fmaf(w, bhi(ev.x), a1);
                a2 = fmaf(w, blo(ev.y), a2); a3 = fmaf(w, bhi(ev.y), a3);
            }
            ((float4*)part)[wv * 64 + ln] = make_float4(a0, a1, a2, a3);
        }
        __syncthreads();
        if (tid < 256) {
            float s = 0.f;
            #pragma unroll
            for (int w2 = 0; w2 < 12; ++w2) s += part[w2][tid];
            const float s1 = __shfl_down(s, 1);
            if (!(tid & 1)) ((unsigned*)xcat)[64 + (tid >> 1)] = pkh(s, s1);  // att f16
        }
        __syncthreads();

        // ---- P3: d0 = [h_a' | att] @ pjW^T + pjb  (split-K by 2) ----
        if (tid < 512) {
            const int half = tid >> 8, idx = tid & 255;
            const uint4* wp = pjWH + (size_t)half * 32 * 256 + idx;
            const uint4* src = half ? (const uint4*)(xcat + 16) : (const uint4*)ha_h;
            float s = 0.f;
            #pragma unroll 8
            for (int k8 = 0; k8 < 32; ++k8) {
                const uint4 w = wp[(size_t)k8 * 256], a = src[k8];
                s = dot2(w.x, a.x, s); s = dot2(w.y, a.y, s);
                s = dot2(w.z, a.z, s); s = dot2(w.w, a.w, s);
            }
            part[half][idx] = s;
        }
        __syncthreads();
        if (tid < 256) {
            const float d0 = part[0][tid] + part[1][tid] + pjb[tid];
            d0s[tid] = d0;
            const float dq = __shfl_down(d0, 1);
            if (!(tid & 1)) d0_h[tid >> 1] = pkh(d0, dq);
        }
        __syncthreads();

        // ---- P4: dec1 GRU; d1 = h1' + d0 ----
        {
            float ai = 0.f, ah = 0.f;
            const uint4* wp = w1ihH + tid;
            const uint4* xc = (const uint4*)d0_h;
            #pragma unroll 8
            for (int k8 = 0; k8 < 32; ++k8) {
                const uint4 w = wp[(size_t)k8 * 768], a = xc[k8];
                ai = dot2(w.x, a.x, ai); ai = dot2(w.y, a.y, ai);
                ai = dot2(w.z, a.z, ai); ai = dot2(w.w, a.w, ai);
            }
            const uint4* wq = w1hhH + tid;
            const uint4* hc = (const uint4*)h1_h;
            #pragma unroll 8
            for (int k8 = 0; k8 < 32; ++k8) {
                const uint4 w = wq[(size_t)k8 * 768], a = hc[k8];
                ah = dot2(w.x, a.x, ah); ah = dot2(w.y, a.y, ah);
                ah = dot2(w.z, a.z, ah); ah = dot2(w.w, a.w, ah);
            }
            gi[tid] = ai + w1bih[tid];
            gh[tid] = ah + w1bhh[tid];
        }
        __syncthreads();
        if (tid < 256) {
            const float r = sigf(gi[tid] + gh[tid]);
            const float z = sigf(gi[256 + tid] + gh[256 + tid]);
            const float n = tanhff(gi[512 + tid] + r * gh[512 + tid]);
            const float hp = (1.f - z) * n + z * h1s[tid];
            h1s[tid] = hp;
            const float d1 = hp + d0s[tid];
            d1s[tid] = d1;
            const float hq = __shfl_down(hp, 1);
            const float dq = __shfl_down(d1, 1);
            if (!(tid & 1)) { h1_h[tid >> 1] = pkh(hp, hq); d1_h[tid >> 1] = pkh(d1, dq); }
        }
        __syncthreads();

        // ---- P5: dec2 GRU; d2 = h2' + d1 -> dall[t] ----
        {
            float ai = 0.f, ah = 0.f;
            const uint4* wp = w2ihH + tid;
            const uint4* xc = (const uint4*)d1_h;
            #pragma unroll 8
            for (int k8 = 0; k8 < 32; ++k8) {
                const uint4 w = wp[(size_t)k8 * 768], a = xc[k8];
                ai = dot2(w.x, a.x, ai); ai = dot2(w.y, a.y, ai);
                ai = dot2(w.z, a.z, ai); ai = dot2(w.w, a.w, ai);
            }
            const uint4* wq = w2hhH + tid;
            const uint4* hc = (const uint4*)h2_h;
            #pragma unroll 8
            for (int k8 = 0; k8 < 32; ++k8) {
                const uint4 w = wq[(size_t)k8 * 768], a = hc[k8];
                ah = dot2(w.x, a.x, ah); ah = dot2(w.y, a.y, ah);
                ah = dot2(w.z, a.z, ah); ah = dot2(w.w, a.w, ah);
            }
            gi[tid] = ai + w2bih[tid];
            gh[tid] = ah + w2bhh[tid];
        }
        __syncthreads();
        if (tid < 256) {
            const float r = sigf(gi[tid] + gh[tid]);
            const float z = sigf(gi[256 + tid] + gh[256 + tid]);
            const float n = tanhff(gi[512 + tid] + r * gh[512 + tid]);
            const float hp = (1.f - z) * n + z * h2s[tid];
            h2s[tid] = hp;
            dall[((size_t)t * 256 + b) * 256 + tid] = hp + d1s[tid];
            const float hq = __shfl_down(hp, 1);
            if (!(tid & 1)) h2_h[tid >> 1] = pkh(hp, hq);
        }
        __syncthreads();
    }
}

// ---------------------------------------------------------------------------
extern "C" void kernel_launch(void* const* d_in, const int* in_sizes, int n_in,
                              void* d_out, int out_size, void* d_ws, size_t ws_size,
                              hipStream_t stream)
{
    const float* enc    = (const float*)d_in[0];
    const float* inputs = (const float*)d_in[1];
    const int*   mlen   = (const int*)d_in[2];
    const float* pW1 = (const float*)d_in[3];  const float* pb1 = (const float*)d_in[4];
    const float* pW2 = (const float*)d_in[5];  const float* pb2 = (const float*)d_in[6];
    const float* aWih = (const float*)d_in[7]; const float* abih = (const float*)d_in[8];
    const float* aWhh = (const float*)d_in[9]; const float* abhh = (const float*)d_in[10];
    const float* memW = (const float*)d_in[11];
    const float* qW   = (const float*)d_in[12];
    const float* vW   = (const float*)d_in[13];
    const float* pjW  = (const float*)d_in[14]; const float* pjb = (const float*)d_in[15];
    const float* w1ih = (const float*)d_in[16]; const float* w1bih = (const float*)d_in[17];
    const float* w1hh = (const float*)d_in[18]; const float* w1bhh = (const float*)d_in[19];
    const float* w2ih = (const float*)d_in[20]; const float* w2bih = (const float*)d_in[21];
    const float* w2hh = (const float*)d_in[22]; const float* w2bhh = (const float*)d_in[23];
    const float* melW = (const float*)d_in[24]; const float* melb = (const float*)d_in[25];

    float* out = (float*)d_out;
    float* ws  = (float*)d_ws;

    // workspace (float units)
    float* X1   = ws;                          // [51200,256] fp32 (aliased dall)
    float* dall = X1;                          // 13,107,200
    unsigned* X2h = (unsigned*)(ws + 13107200);          // 3,276,800 uints (f16 x2)
    unsigned short* pmH  = (unsigned short*)(ws + 16384000);  // bf16 pm
    unsigned short* encH = (unsigned short*)(ws + 22937600);  // bf16 enc
    uint4* aWihH = (uint4*)(ws + 29491200);    // 48*768
    uint4* aWhhH = aWihH + 36864;              // 32*768
    uint4* w1ihH = aWhhH + 24576;
    uint4* w1hhH = w1ihH + 24576;
    uint4* w2ihH = w1hhH + 24576;
    uint4* w2hhH = w2ihH + 24576;
    uint4* pjWH  = w2hhH + 24576;              // 64*256
    uint4* qWH   = pjWH + 16384;               // 32*256

    // pack weights to f16 [K/8][N]
    pack_wh<<<64, 256, 0, stream>>>(aWih, aWihH, 768, 384);
    pack_wh<<<64, 256, 0, stream>>>(aWhh, aWhhH, 768, 256);
    pack_wh<<<64, 256, 0, stream>>>(w1ih, w1ihH, 768, 256);
    pack_wh<<<64, 256, 0, stream>>>(w1hh, w1hhH, 768, 256);
    pack_wh<<<64, 256, 0, stream>>>(w2ih, w2ihH, 768, 256);
    pack_wh<<<64, 256, 0, stream>>>(w2hh, w2hhH, 768, 256);
    pack_wh<<<64, 256, 0, stream>>>(pjW,  pjWH,  256, 512);
    pack_wh<<<64, 256, 0, stream>>>(qW,   qWH,   256, 256);
    pack_bf16<<<1024, 256, 0, stream>>>(enc, encH, 13107200);

    // prenet1: X1 = relu(prev @ W1^T + b1)  fp32
    gemm128<2, 1><<<dim3(400, 2), 256, 0, stream>>>(
        inputs, 0, pW1, 400, pb1, X1, 256, 51200, 256, 400);
    // prenet2: X2 = relu(X1 @ W2^T + b2)  stored f16 (64 uints / row)
    gemm128<0, 4><<<dim3(400, 1), 256, 0, stream>>>(
        X1, 256, pW2, 256, pb2, (float*)X2h, 128, 51200, 128, 256);
    // processed_memory = enc @ memW^T  stored bf16
    gemm128<0, 3><<<dim3(400, 2), 256, 0, stream>>>(
        enc, 256, memW, 256, nullptr, (float*)pmH, 256, 51200, 256, 256);

    // zero-barrier persistent decoder: one batch row per block
    decoder_loop<<<256, 768, 0, stream>>>(
        (const uint4*)X2h, pmH, encH, mlen,
        aWihH, abih, aWhhH, abhh, qWH, vW, pjWH, pjb,
        w1ihH, w1bih, w1hhH, w1bhh, w2ihH, w2bih, w2hhH, w2bhh,
        dall, out + ALIGN_OFF);

    // mel projection: out[b,t,:] = dall[t,b,:] @ melW^T + melb
    gemm128<0, 2><<<dim3(400, 4), 256, 0, stream>>>(
        dall, 256, melW, 256, melb, out, 400, 51200, 400, 256);
}

// Round 10
// 7993.584 us; speedup vs baseline: 7.4259x; 1.0266x over previous
//
#include <hip/hip_runtime.h>
#include <math.h>

// B=256, T_ENC=200, D=256, T_MEL=1000, NMEL=80, R=5, IN_R=400, Td=200
#define ALIGN_OFF 20480000   // 256*200*400

typedef __fp16 h2_t __attribute__((ext_vector_type(2)));

__device__ __forceinline__ float sigf(float x) {
    return __builtin_amdgcn_rcpf(1.0f + __expf(-x));
}
__device__ __forceinline__ float tanhff(float x) {
    float e = __expf(2.0f * x);
    return 1.0f - 2.0f * __builtin_amdgcn_rcpf(e + 1.0f);
}
__device__ __forceinline__ unsigned short f2bf(float x) {
    unsigned u = __float_as_uint(x);
    return (unsigned short)((u + 0x7FFFu + ((u >> 16) & 1u)) >> 16);
}
__device__ __forceinline__ float blo(unsigned u) { return __uint_as_float(u << 16); }
__device__ __forceinline__ float bhi(unsigned u) { return __uint_as_float(u & 0xffff0000u); }
// pack two f32 -> f16x2 (RTZ)
__device__ __forceinline__ unsigned pkh(float a, float b) {
    h2_t r = __builtin_amdgcn_cvt_pkrtz(a, b);
    return __builtin_bit_cast(unsigned, r);
}
// f16 pair dot with f32 accumulate
__device__ __forceinline__ float dot2(unsigned w, unsigned a, float c) {
#if __has_builtin(__builtin_amdgcn_fdot2)
    return __builtin_amdgcn_fdot2(__builtin_bit_cast(h2_t, w),
                                  __builtin_bit_cast(h2_t, a), c, false);
#else
    h2_t wv = __builtin_bit_cast(h2_t, w), av = __builtin_bit_cast(h2_t, a);
    return c + (float)wv.x * (float)av.x + (float)wv.y * (float)av.y;
#endif
}

// ---------------------------------------------------------------------------
// 128x128-tile fp32 GEMM (prenet / processed_memory / mel).
// AMODE: 0 plain; 2 teacher-forcing virtual A (prenet1)
// EPI: 0 plain, 1 relu, 2 mel-layout store, 3 bf16 store (ld 256),
//      4 relu + f16 store (ld 128 halves = 64 uints)
// ---------------------------------------------------------------------------
template<int AMODE, int EPI>
__global__ __launch_bounds__(256)
void gemm128(const float* __restrict__ A, int lda,
             const float* __restrict__ W, int ldw,
             const float* __restrict__ bias,
             float* __restrict__ C, int ldc, int M, int N, int K)
{
    __shared__ float As[16][128];
    __shared__ float Bs[16][128];
    const int m0 = blockIdx.x * 128, n0 = blockIdx.y * 128;
    const int tid = threadIdx.x;
    const int tx = tid & 15, ty = tid >> 4;
    float acc[8][8] = {};
    for (int k0 = 0; k0 < K; k0 += 16) {
        {
            const int m = tid >> 1, h = (tid & 1) * 8;
            const int grow = m0 + m;
            float4 a0, a1;
            if (AMODE == 2) {
                int t = grow >> 8, b = grow & 255;
                if (t == 0) { a0 = make_float4(0, 0, 0, 0); a1 = a0; }
                else {
                    const float* p = A + (size_t)b * 80000 + (t - 1) * 400 + k0 + h;
                    a0 = *(const float4*)p; a1 = *(const float4*)(p + 4);
                }
            } else {
                const float* p = A + (size_t)grow * lda + k0 + h;
                a0 = *(const float4*)p; a1 = *(const float4*)(p + 4);
            }
            As[h + 0][m] = a0.x; As[h + 1][m] = a0.y; As[h + 2][m] = a0.z; As[h + 3][m] = a0.w;
            As[h + 4][m] = a1.x; As[h + 5][m] = a1.y; As[h + 6][m] = a1.z; As[h + 7][m] = a1.w;
            const int gn = n0 + m;
            float4 b0, b1;
            if (gn < N) {
                const float* p = W + (size_t)gn * ldw + k0 + h;
                b0 = *(const float4*)p; b1 = *(const float4*)(p + 4);
            } else { b0 = make_float4(0, 0, 0, 0); b1 = b0; }
            Bs[h + 0][m] = b0.x; Bs[h + 1][m] = b0.y; Bs[h + 2][m] = b0.z; Bs[h + 3][m] = b0.w;
            Bs[h + 4][m] = b1.x; Bs[h + 5][m] = b1.y; Bs[h + 6][m] = b1.z; Bs[h + 7][m] = b1.w;
        }
        __syncthreads();
        #pragma unroll
        for (int kk = 0; kk < 16; ++kk) {
            float av[8], bv[8];
            *(float4*)&av[0] = *(const float4*)&As[kk][ty * 8];
            *(float4*)&av[4] = *(const float4*)&As[kk][ty * 8 + 4];
            *(float4*)&bv[0] = *(const float4*)&Bs[kk][tx * 8];
            *(float4*)&bv[4] = *(const float4*)&Bs[kk][tx * 8 + 4];
            #pragma unroll
            for (int i = 0; i < 8; ++i)
                #pragma unroll
                for (int j = 0; j < 8; ++j)
                    acc[i][j] += av[i] * bv[j];
        }
        __syncthreads();
    }
    #pragma unroll
    for (int i = 0; i < 8; ++i) {
        const int row = m0 + ty * 8 + i;
        const int t_ = row >> 8, b_ = row & 255;
        #pragma unroll
        for (int j4 = 0; j4 < 2; ++j4) {
            const int col = n0 + tx * 8 + j4 * 4;
            if (col >= N) continue;
            float4 v;
            float* pv = &v.x;
            #pragma unroll
            for (int u = 0; u < 4; ++u) {
                float x = acc[i][j4 * 4 + u] + (bias ? bias[col + u] : 0.0f);
                if (EPI == 1 || EPI == 4) x = fmaxf(x, 0.0f);
                pv[u] = x;
            }
            if (EPI == 2)      *(float4*)(C + (size_t)b_ * 80000 + t_ * 400 + col) = v;
            else if (EPI == 3) {
                ushort4 o;
                o.x = f2bf(pv[0]); o.y = f2bf(pv[1]); o.z = f2bf(pv[2]); o.w = f2bf(pv[3]);
                *(ushort4*)((unsigned short*)C + (size_t)row * 256 + col) = o;
            } else if (EPI == 4) {
                uint2 o; o.x = pkh(pv[0], pv[1]); o.y = pkh(pv[2], pv[3]);
                *(uint2*)((unsigned*)C + (size_t)row * 64 + (col >> 1)) = o;
            } else *(float4*)(C + (size_t)row * ldc + col) = v;
        }
    }
}

// ---------------------------------------------------------------------------
// Pack W [N][K] f32 -> f16 [K/8][N] uint4 (8 halves per entry).
// ---------------------------------------------------------------------------
__global__ __launch_bounds__(256)
void pack_wh(const float* __restrict__ W, uint4* __restrict__ P, int N, int K)
{
    const int tot = N * (K >> 3);
    for (int i = blockIdx.x * 256 + threadIdx.x; i < tot; i += gridDim.x * 256) {
        const int n = i % N, k8 = i / N;
        const float* s = W + (size_t)n * K + (k8 << 3);
        uint4 o;
        o.x = pkh(s[0], s[1]); o.y = pkh(s[2], s[3]);
        o.z = pkh(s[4], s[5]); o.w = pkh(s[6], s[7]);
        P[(size_t)k8 * N + n] = o;
    }
}

// fp32 -> bf16 elementwise pack
__global__ __launch_bounds__(256)
void pack_bf16(const float* __restrict__ src, unsigned short* __restrict__ dst, int n)
{
    for (int i = (blockIdx.x * 256 + threadIdx.x) * 4; i < n; i += gridDim.x * 1024) {
        float4 v = *(const float4*)(src + i);
        ushort4 o;
        o.x = f2bf(v.x); o.y = f2bf(v.y); o.z = f2bf(v.z); o.w = f2bf(v.w);
        *(ushort4*)(dst + i) = o;
    }
}

// ---------------------------------------------------------------------------
// Zero-barrier persistent decoder: block b owns batch row b completely.
// pm row (step-invariant) LDS-resident; enc streams from L2/L3 (latency-
// tolerant FMA loop); all recurrent state in LDS; weights f16 [K/8][N].
// ---------------------------------------------------------------------------
__global__ __launch_bounds__(768)
void decoder_loop(
    const uint4* __restrict__ X2h4,          // [200*256][16] uint4, f16 prenet out
    const unsigned short* __restrict__ pmH,  // [256][200][256] bf16
    const unsigned short* __restrict__ encH, // [256][200][256] bf16
    const int*   __restrict__ mlen,
    const uint4* __restrict__ aWihH, const float* __restrict__ abih,
    const uint4* __restrict__ aWhhH, const float* __restrict__ abhh,
    const uint4* __restrict__ qWH,   const float* __restrict__ vW,
    const uint4* __restrict__ pjWH,  const float* __restrict__ pjb,
    const uint4* __restrict__ w1ihH, const float* __restrict__ w1bih,
    const uint4* __restrict__ w1hhH, const float* __restrict__ w1bhh,
    const uint4* __restrict__ w2ihH, const float* __restrict__ w2bih,
    const uint4* __restrict__ w2hhH, const float* __restrict__ w2bhh,
    float* __restrict__ dall, float* __restrict__ alout)
{
    __shared__ unsigned short pmS[51200];    // this row's pm, bf16 (100 KB)
    __shared__ uint4 xcat[48];               // f16 [x2_t (16) | att (32)]
    __shared__ unsigned ha_h[128], h1_h[128], h2_h[128], d0_h[128], d1_h[128];
    __shared__ float hA[256], h1s[256], h2s[256], d0s[256], d1s[256];
    __shared__ float qv[256], vvS[256];
    __shared__ float sc[200], al[208];
    __shared__ float gi[768], gh[768];
    __shared__ float part[12][256];

    const int b = blockIdx.x, tid = threadIdx.x;
    const int wv = tid >> 6, ln = tid & 63;
    const unsigned short* encG = encH + (size_t)b * 51200;

    // one-time init: pm row -> LDS (step-invariant), states zero
    {
        const uint4* psrc = (const uint4*)(pmH + (size_t)b * 51200);
        for (int i = tid; i < 6400; i += 768) ((uint4*)pmS)[i] = psrc[i];
        if (tid < 256) { vvS[tid] = vW[tid]; hA[tid] = 0.f; h1s[tid] = 0.f; h2s[tid] = 0.f; }
        if (tid < 128) { ha_h[tid] = 0u; h1_h[tid] = 0u; h2_h[tid] = 0u; }
        if (tid < 32)  xcat[16 + tid] = make_uint4(0, 0, 0, 0);   // att = 0
    }
    const int len = mlen[b];
    __syncthreads();

    for (int t = 0; t < 200; ++t) {
        // ---- P1: attention GRU  h_a' = GRU([x2_t | att], h_a) ----
        if (tid < 16) xcat[tid] = X2h4[((size_t)t * 256 + b) * 16 + tid];
        __syncthreads();
        {
            float ai = 0.f, ah = 0.f;
            const uint4* wp = aWihH + tid;
            #pragma unroll 8
            for (int k8 = 0; k8 < 48; ++k8) {
                const uint4 w = wp[(size_t)k8 * 768], a = xcat[k8];
                ai = dot2(w.x, a.x, ai); ai = dot2(w.y, a.y, ai);
                ai = dot2(w.z, a.z, ai); ai = dot2(w.w, a.w, ai);
            }
            const uint4* wq = aWhhH + tid;
            const uint4* hc = (const uint4*)ha_h;
            #pragma unroll 8
            for (int k8 = 0; k8 < 32; ++k8) {
                const uint4 w = wq[(size_t)k8 * 768], a = hc[k8];
                ah = dot2(w.x, a.x, ah); ah = dot2(w.y, a.y, ah);
                ah = dot2(w.z, a.z, ah); ah = dot2(w.w, a.w, ah);
            }
            gi[tid] = ai + abih[tid];
            gh[tid] = ah + abhh[tid];
        }
        __syncthreads();
        if (tid < 256) {
            const float r = sigf(gi[tid] + gh[tid]);
            const float z = sigf(gi[256 + tid] + gh[256 + tid]);
            const float n = tanhff(gi[512 + tid] + r * gh[512 + tid]);
            const float hp = (1.f - z) * n + z * hA[tid];
            hA[tid] = hp;
            const float hq = __shfl_down(hp, 1);
            if (!(tid & 1)) ha_h[tid >> 1] = pkh(hp, hq);
        }
        __syncthreads();

        // ---- P2: q = h_a' @ qW^T ----
        if (tid < 256) {
            float s = 0.f;
            const uint4* qp = qWH + tid;
            const uint4* hc = (const uint4*)ha_h;
            #pragma unroll 8
            for (int k8 = 0; k8 < 32; ++k8) {
                const uint4 w = qp[(size_t)k8 * 256], a = hc[k8];
                s = dot2(w.x, a.x, s); s = dot2(w.y, a.y, s);
                s = dot2(w.z, a.z, s); s = dot2(w.w, a.w, s);
            }
            qv[tid] = s;
        }
        __syncthreads();
        // ---- scores from LDS pm: sc[i] = v . tanh(pm[i] + q), i < len ----
        {
            const float4 q4 = ((const float4*)qv)[ln];
            const float4 v4 = ((const float4*)vvS)[ln];
            for (int i = wv; i < 200; i += 12) {
                if (i < len) {
                    const uint2 pr = *(const uint2*)(pmS + i * 256 + ln * 4);
                    float p = v4.x * tanhff(blo(pr.x) + q4.x)
                            + v4.y * tanhff(bhi(pr.x) + q4.y)
                            + v4.z * tanhff(blo(pr.y) + q4.z)
                            + v4.w * tanhff(bhi(pr.y) + q4.w);
                    #pragma unroll
                    for (int off = 32; off; off >>= 1) p += __shfl_down(p, off);
                    if (ln == 0) sc[i] = p;
                } else if (ln == 0) sc[i] = -1e9f;
            }
        }
        __syncthreads();
        if (wv == 0) {
            float v0 = sc[ln], v1 = sc[ln + 64], v2 = sc[ln + 128];
            float v3 = (ln < 8) ? sc[ln + 192] : -1e30f;
            float mx = fmaxf(fmaxf(v0, v1), fmaxf(v2, v3));
            #pragma unroll
            for (int off = 32; off; off >>= 1) mx = fmaxf(mx, __shfl_xor(mx, off));
            float e0 = __expf(v0 - mx), e1 = __expf(v1 - mx), e2 = __expf(v2 - mx);
            float e3 = (ln < 8) ? __expf(v3 - mx) : 0.f;
            float ss = e0 + e1 + e2 + e3;
            #pragma unroll
            for (int off = 32; off; off >>= 1) ss += __shfl_xor(ss, off);
            const float inv = 1.0f / ss;
            float* ao = alout + (size_t)b * 40000 + (size_t)t * 200;
            al[ln]       = e0 * inv; ao[ln]       = e0 * inv;
            al[ln + 64]  = e1 * inv; ao[ln + 64]  = e1 * inv;
            al[ln + 128] = e2 * inv; ao[ln + 128] = e2 * inv;
            if (ln < 8) { al[ln + 192] = e3 * inv; ao[ln + 192] = e3 * inv; }
        }
        __syncthreads();
        // ---- context: att = align @ enc (enc streamed, al[i>=len]==0) ----
        {
            float a0 = 0.f, a1 = 0.f, a2 = 0.f, a3 = 0.f;
            for (int i = wv; i < len; i += 12) {
                const float w = al[i];
                const uint2 ev = *(const uint2*)(encG + i * 256 + ln * 4);
                a0 = fmaf(w, blo(ev.x), a0); a1 = fmaf(w, bhi(ev.x), a1);
                a2 = fmaf(w, blo(ev.y), a2); a3 = fmaf(w, bhi(ev.y), a3);
            }
            ((float4*)part)[wv * 64 + ln] = make_float4(a0, a1, a2, a3);
        }
        __syncthreads();
        if (tid < 256) {
            float s = 0.f;
            #pragma unroll
            for (int w2 = 0; w2 < 12; ++w2) s += part[w2][tid];
            const float s1 = __shfl_down(s, 1);
            if (!(tid & 1)) ((unsigned*)xcat)[64 + (tid >> 1)] = pkh(s, s1);  // att f16
        }
        __syncthreads();

        // ---- P3: d0 = [h_a' | att] @ pjW^T + pjb  (split-K by 2) ----
        if (tid < 512) {
            const int half = tid >> 8, idx = tid & 255;
            const uint4* wp = pjWH + (size_t)half * 32 * 256 + idx;
            const uint4* src = half ? (const uint4*)(xcat + 16) : (const uint4*)ha_h;
            float s = 0.f;
            #pragma unroll 8
            for (int k8 = 0; k8 < 32; ++k8) {
                const uint4 w = wp[(size_t)k8 * 256], a = src[k8];
                s = dot2(w.x, a.x, s); s = dot2(w.y, a.y, s);
                s = dot2(w.z, a.z, s); s = dot2(w.w, a.w, s);
            }
            part[half][idx] = s;
        }
        __syncthreads();
        if (tid < 256) {
            const float d0 = part[0][tid] + part[1][tid] + pjb[tid];
            d0s[tid] = d0;
            const float dq = __shfl_down(d0, 1);
            if (!(tid & 1)) d0_h[tid >> 1] = pkh(d0, dq);
        }
        __syncthreads();

        // ---- P4: dec1 GRU; d1 = h1' + d0 ----
        {
            float ai = 0.f, ah = 0.f;
            const uint4* wp = w1ihH + tid;
            const uint4* xc = (const uint4*)d0_h;
            #pragma unroll 8
            for (int k8 = 0; k8 < 32; ++k8) {
                const uint4 w = wp[(size_t)k8 * 768], a = xc[k8];
                ai = dot2(w.x, a.x, ai); ai = dot2(w.y, a.y, ai);
                ai = dot2(w.z, a.z, ai); ai = dot2(w.w, a.w, ai);
            }
            const uint4* wq = w1hhH + tid;
            const uint4* hc = (const uint4*)h1_h;
            #pragma unroll 8
            for (int k8 = 0; k8 < 32; ++k8) {
                const uint4 w = wq[(size_t)k8 * 768], a = hc[k8];
                ah = dot2(w.x, a.x, ah); ah = dot2(w.y, a.y, ah);
                ah = dot2(w.z, a.z, ah); ah = dot2(w.w, a.w, ah);
            }
            gi[tid] = ai + w1bih[tid];
            gh[tid] = ah + w1bhh[tid];
        }
        __syncthreads();
        if (tid < 256) {
            const float r = sigf(gi[tid] + gh[tid]);
            const float z = sigf(gi[256 + tid] + gh[256 + tid]);
            const float n = tanhff(gi[512 + tid] + r * gh[512 + tid]);
            const float hp = (1.f - z) * n + z * h1s[tid];
            h1s[tid] = hp;
            const float d1 = hp + d0s[tid];
            d1s[tid] = d1;
            const float hq = __shfl_down(hp, 1);
            const float dq = __shfl_down(d1, 1);
            if (!(tid & 1)) { h1_h[tid >> 1] = pkh(hp, hq); d1_h[tid >> 1] = pkh(d1, dq); }
        }
        __syncthreads();

        // ---- P5: dec2 GRU; d2 = h2' + d1 -> dall[t] ----
        {
            float ai = 0.f, ah = 0.f;
            const uint4* wp = w2ihH + tid;
            const uint4* xc = (const uint4*)d1_h;
            #pragma unroll 8
            for (int k8 = 0; k8 < 32; ++k8) {
                const uint4 w = wp[(size_t)k8 * 768], a = xc[k8];
                ai = dot2(w.x, a.x, ai); ai = dot2(w.y, a.y, ai);
                ai = dot2(w.z, a.z, ai); ai = dot2(w.w, a.w, ai);
            }
            const uint4* wq = w2hhH + tid;
            const uint4* hc = (const uint4*)h2_h;
            #pragma unroll 8
            for (int k8 = 0; k8 < 32; ++k8) {
                const uint4 w = wq[(size_t)k8 * 768], a = hc[k8];
                ah = dot2(w.x, a.x, ah); ah = dot2(w.y, a.y, ah);
                ah = dot2(w.z, a.z, ah); ah = dot2(w.w, a.w, ah);
            }
            gi[tid] = ai + w2bih[tid];
            gh[tid] = ah + w2bhh[tid];
        }
        __syncthreads();
        if (tid < 256) {
            const float r = sigf(gi[tid] + gh[tid]);
            const float z = sigf(gi[256 + tid] + gh[256 + tid]);
            const float n = tanhff(gi[512 + tid] + r * gh[512 + tid]);
            const float hp = (1.f - z) * n + z * h2s[tid];
            h2s[tid] = hp;
            dall[((size_t)t * 256 + b) * 256 + tid] = hp + d1s[tid];
            const float hq = __shfl_down(hp, 1);
            if (!(tid & 1)) h2_h[tid >> 1] = pkh(hp, hq);
        }
        __syncthreads();
    }
}

// ---------------------------------------------------------------------------
extern "C" void kernel_launch(void* const* d_in, const int* in_sizes, int n_in,
                              void* d_out, int out_size, void* d_ws, size_t ws_size,
                              hipStream_t stream)
{
    const float* enc    = (const float*)d_in[0];
    const float* inputs = (const float*)d_in[1];
    const int*   mlen   = (const int*)d_in[2];
    const float* pW1 = (const float*)d_in[3];  const float* pb1 = (const float*)d_in[4];
    const float* pW2 = (const float*)d_in[5];  const float* pb2 = (const float*)d_in[6];
    const float* aWih = (const float*)d_in[7]; const float* abih = (const float*)d_in[8];
    const float* aWhh = (const float*)d_in[9]; const float* abhh = (const float*)d_in[10];
    const float* memW = (const float*)d_in[11];
    const float* qW   = (const float*)d_in[12];
    const float* vW   = (const float*)d_in[13];
    const float* pjW  = (const float*)d_in[14]; const float* pjb = (const float*)d_in[15];
    const float* w1ih = (const float*)d_in[16]; const float* w1bih = (const float*)d_in[17];
    const float* w1hh = (const float*)d_in[18]; const float* w1bhh = (const float*)d_in[19];
    const float* w2ih = (const float*)d_in[20]; const float* w2bih = (const float*)d_in[21];
    const float* w2hh = (const float*)d_in[22]; const float* w2bhh = (const float*)d_in[23];
    const float* melW = (const float*)d_in[24]; const float* melb = (const float*)d_in[25];

    float* out = (float*)d_out;
    float* ws  = (float*)d_ws;

    // workspace (float units)
    float* X1   = ws;                          // [51200,256] fp32 (aliased dall)
    float* dall = X1;                          // 13,107,200
    unsigned* X2h = (unsigned*)(ws + 13107200);          // 3,276,800 uints (f16 x2)
    unsigned short* pmH  = (unsigned short*)(ws + 16384000);  // bf16 pm
    unsigned short* encH = (unsigned short*)(ws + 22937600);  // bf16 enc
    uint4* aWihH = (uint4*)(ws + 29491200);    // 48*768
    uint4* aWhhH = aWihH + 36864;              // 32*768
    uint4* w1ihH = aWhhH + 24576;
    uint4* w1hhH = w1ihH + 24576;
    uint4* w2ihH = w1hhH + 24576;
    uint4* w2hhH = w2ihH + 24576;
    uint4* pjWH  = w2hhH + 24576;              // 64*256
    uint4* qWH   = pjWH + 16384;               // 32*256

    // pack weights to f16 [K/8][N]
    pack_wh<<<64, 256, 0, stream>>>(aWih, aWihH, 768, 384);
    pack_wh<<<64, 256, 0, stream>>>(aWhh, aWhhH, 768, 256);
    pack_wh<<<64, 256, 0, stream>>>(w1ih, w1ihH, 768, 256);
    pack_wh<<<64, 256, 0, stream>>>(w1hh, w1hhH, 768, 256);
    pack_wh<<<64, 256, 0, stream>>>(w2ih, w2ihH, 768, 256);
    pack_wh<<<64, 256, 0, stream>>>(w2hh, w2hhH, 768, 256);
    pack_wh<<<64, 256, 0, stream>>>(pjW,  pjWH,  256, 512);
    pack_wh<<<64, 256, 0, stream>>>(qW,   qWH,   256, 256);
    pack_bf16<<<1024, 256, 0, stream>>>(enc, encH, 13107200);

    // prenet1: X1 = relu(prev @ W1^T + b1)  fp32
    gemm128<2, 1><<<dim3(400, 2), 256, 0, stream>>>(
        inputs, 0, pW1, 400, pb1, X1, 256, 51200, 256, 400);
    // prenet2: X2 = relu(X1 @ W2^T + b2)  stored f16 (64 uints / row)
    gemm128<0, 4><<<dim3(400, 1), 256, 0, stream>>>(
        X1, 256, pW2, 256, pb2, (float*)X2h, 128, 51200, 128, 256);
    // processed_memory = enc @ memW^T  stored bf16
    gemm128<0, 3><<<dim3(400, 2), 256, 0, stream>>>(
        enc, 256, memW, 256, nullptr, (float*)pmH, 256, 51200, 256, 256);

    // zero-barrier persistent decoder: one batch row per block
    decoder_loop<<<256, 768, 0, stream>>>(
        (const uint4*)X2h, pmH, encH, mlen,
        aWihH, abih, aWhhH, abhh, qWH, vW, pjWH, pjb,
        w1ihH, w1bih, w1hhH, w1bhh, w2ihH, w2bih, w2hhH, w2bhh,
        dall, out + ALIGN_OFF);

    // mel projection: out[b,t,:] = dall[t,b,:] @ melW^T + melb
    gemm128<0, 2><<<dim3(400, 4), 256, 0, stream>>>(
        dall, 256, melW, 256, melb, out, 400, 51200, 400, 256);
}